// Round 8
// baseline (276.355 us; speedup 1.0000x reference)
//
#include <hip/hip_runtime.h>

// ---------------------------------------------------------------------------
// Debiased Representation Loss — fused MI355X implementation (R8).
// Symmetric contrastive kernel (528 upper-triangle tile blocks) made
// structurally spill-proof: ONE 64-AGPR accumulator reused across four
// phases; M and S GEMMs in separate K-loops each with 4-buffer / 128-K
// per barrier-pair staging (same barrier count + DMA depth as the fused
// variant, half the peak registers).
//   M : mask GEMM (bn.bn^T) K=768 -> mb (2 regs)
//   S : sim GEMM (zn.zn^T) K=768 -> svp[32]+dsum[16] regs
//   svT (sv[j][i], 8-elem XOR-swizzle, b64 writes) + maskT into freed S2/S3
//   A1: direct attn K=256 (S0/S1 staging) -> combine from regs (R4 path)
//   A2: transposed attn -> combine from svT/maskT LDS
// ---------------------------------------------------------------------------

#define B_N   4096
#define D_N   768
#define HID_N 256
#define NCLS  200

typedef __attribute__((ext_vector_type(8))) short v8s;   // 8 x bf16 (4 VGPRs)
typedef __attribute__((ext_vector_type(4))) float v4f;   // MFMA accumulator

__device__ __forceinline__ unsigned short f2bf(float x) {
    unsigned int u = __float_as_uint(x);
    unsigned int r = (u + 0x7FFFu + ((u >> 16) & 1u)) >> 16;
    return (unsigned short)r;
}
__device__ __forceinline__ float bf2f(unsigned short h) {
    return __uint_as_float((unsigned int)h << 16);
}

// async global->LDS, 16 B per lane; lane i lands at ldsbase + i*16
__device__ __forceinline__ void gld16(const unsigned short* g, unsigned short* l) {
    __builtin_amdgcn_global_load_lds(
        (__attribute__((address_space(1))) void*)g,
        (__attribute__((address_space(3))) void*)l, 16, 0, 0);
}

#define ZERO_ACC(a) { _Pragma("unroll") for (int _i = 0; _i < 4; _i++) \
    _Pragma("unroll") for (int _j = 0; _j < 4; _j++) a[_i][_j] = (v4f){0.f,0.f,0.f,0.f}; }

// ---------------------------------------------------------------------------
// Kernel 1: pre-pass. blocks [0,4096): row normalize; [4096,4352): softmax
// partials (block 4096 also zeroes accums).
// ---------------------------------------------------------------------------
__global__ __launch_bounds__(256) void pre_all(
    const float* __restrict__ z, const float* __restrict__ base,
    const float* __restrict__ logits, const int* __restrict__ oldi,
    const int* __restrict__ newi,
    unsigned short* __restrict__ zn, unsigned short* __restrict__ bn,
    float* __restrict__ mpart, float* __restrict__ accums)
{
    int tid = threadIdx.x;
    if (blockIdx.x < B_N) {
        int row = blockIdx.x;
        __shared__ float ws1[4], ws2[4];
        const float* zr = z    + (size_t)row * D_N;
        const float* br = base + (size_t)row * D_N;
        float z0 = zr[tid], z1 = zr[tid + 256], z2 = zr[tid + 512];
        float b0 = br[tid], b1 = br[tid + 256], b2 = br[tid + 512];
        float s1 = z0*z0 + z1*z1 + z2*z2;
        float s2 = b0*b0 + b1*b1 + b2*b2;
        #pragma unroll
        for (int m = 32; m > 0; m >>= 1) { s1 += __shfl_xor(s1, m); s2 += __shfl_xor(s2, m); }
        if ((tid & 63) == 0) { ws1[tid >> 6] = s1; ws2[tid >> 6] = s2; }
        __syncthreads();
        float t1 = ws1[0] + ws1[1] + ws1[2] + ws1[3];
        float t2 = ws2[0] + ws2[1] + ws2[2] + ws2[3];
        float sc1 = 1.0f / fmaxf(sqrtf(t1), 1e-12f);
        float sc2 = 1.0f / fmaxf(sqrtf(t2), 1e-12f);
        size_t o = (size_t)row * D_N;
        zn[o+tid] = f2bf(z0*sc1); zn[o+tid+256] = f2bf(z1*sc1); zn[o+tid+512] = f2bf(z2*sc1);
        bn[o+tid] = f2bf(b0*sc2); bn[o+tid+256] = f2bf(b1*sc2); bn[o+tid+512] = f2bf(b2*sc2);
        return;
    }
    // softmax partials: 256 blocks x 16 rows
    {
        __shared__ int act[256];
        __shared__ float accs[4][256];
        int sb = blockIdx.x - B_N;
        int lane = tid & 63, wave = tid >> 6;
        if (sb == 0 && tid < 4) accums[tid] = 0.0f;
        if (tid < NCLS) act[tid] = (tid < 100) ? oldi[tid] : newi[tid - 100];
        accs[0][tid] = 0.f; accs[1][tid] = 0.f; accs[2][tid] = 0.f; accs[3][tid] = 0.f;
        __syncthreads();
        int a0 = act[lane], a1 = act[lane + 64], a2 = act[lane + 128];
        int a3 = (lane < 8) ? act[lane + 192] : 0;
        int r0 = sb * 16 + wave * 4;
        float c0 = 0.f, c1 = 0.f, c2 = 0.f, c3 = 0.f;
        for (int i = 0; i < 4; i++) {
            const float* lr = logits + (size_t)(r0 + i) * NCLS;
            float x0 = lr[a0], x1 = lr[a1], x2 = lr[a2];
            float x3 = (lane < 8) ? lr[a3] : -3.0e38f;
            float m = fmaxf(fmaxf(x0, x1), fmaxf(x2, x3));
            #pragma unroll
            for (int s = 32; s > 0; s >>= 1) m = fmaxf(m, __shfl_xor(m, s));
            float e0 = __expf(x0 - m), e1 = __expf(x1 - m), e2 = __expf(x2 - m);
            float e3 = (lane < 8) ? __expf(x3 - m) : 0.f;
            float sm = e0 + e1 + e2 + e3;
            #pragma unroll
            for (int s = 32; s > 0; s >>= 1) sm += __shfl_xor(sm, s);
            float inv = 1.0f / sm;
            c0 += e0 * inv; c1 += e1 * inv; c2 += e2 * inv; c3 += e3 * inv;
        }
        accs[wave][lane] = c0; accs[wave][lane + 64] = c1; accs[wave][lane + 128] = c2;
        if (lane < 8) accs[wave][lane + 192] = c3;
        __syncthreads();
        mpart[(size_t)tid * 256 + sb] =
            accs[0][tid] + accs[1][tid] + accs[2][tid] + accs[3][tid];
    }
}

// ---------------------------------------------------------------------------
// Kernel 2: fz = z @ W^T + b for both weights (f32 in, inline bf16 convert).
// grid (32, 4): y<2 -> f1 (cols y*128), y>=2 -> f2.
// ---------------------------------------------------------------------------
__global__ __launch_bounds__(256, 2) void fz_gemm(
    const float* __restrict__ z,
    const float* __restrict__ w1, const float* __restrict__ w2,
    const float* __restrict__ b1, const float* __restrict__ b2,
    unsigned short* __restrict__ f1z, unsigned short* __restrict__ f2z)
{
    __shared__ __align__(16) unsigned short Al[128 * 72];
    __shared__ __align__(16) unsigned short Bl[128 * 72];
    int which = blockIdx.y >> 1;
    const float* wsrc = which ? w2 : w1;
    const float* bias = which ? b2 : b1;
    unsigned short* outz = which ? f2z : f1z;
    int mBase = blockIdx.x * 128, nBase = (blockIdx.y & 1) * 128;
    int tid = threadIdx.x, lane = tid & 63, wave = tid >> 6, quad = lane >> 4, col = lane & 15;
    int wr = wave >> 1, wc = wave & 1;
    v4f acc[4][4]; ZERO_ACC(acc);
    for (int kc = 0; kc < D_N; kc += 64) {
        __syncthreads();
        #pragma unroll
        for (int s = 0; s < 8; s++) {
            int slot = s * 256 + tid;
            int row = slot >> 4, k4 = slot & 15;
            float4 va = *(const float4*)(z + (size_t)(mBase + row) * D_N + kc + k4 * 4);
            float4 vb = *(const float4*)(wsrc + (size_t)(nBase + row) * D_N + kc + k4 * 4);
            unsigned short* pa = Al + row * 72 + k4 * 4;
            unsigned short* pb = Bl + row * 72 + k4 * 4;
            pa[0] = f2bf(va.x); pa[1] = f2bf(va.y); pa[2] = f2bf(va.z); pa[3] = f2bf(va.w);
            pb[0] = f2bf(vb.x); pb[1] = f2bf(vb.y); pb[2] = f2bf(vb.z); pb[3] = f2bf(vb.w);
        }
        __syncthreads();
        #pragma unroll
        for (int kk = 0; kk < 2; kk++) {
            v8s af[4], bf[4];
            #pragma unroll
            for (int t = 0; t < 4; t++) {
                af[t] = *(const v8s*)(Al + (wr * 64 + t * 16 + col) * 72 + kk * 32 + quad * 8);
                bf[t] = *(const v8s*)(Bl + (wc * 64 + t * 16 + col) * 72 + kk * 32 + quad * 8);
            }
            #pragma unroll
            for (int tr = 0; tr < 4; tr++)
                #pragma unroll
                for (int tc = 0; tc < 4; tc++)
                    acc[tr][tc] = __builtin_amdgcn_mfma_f32_16x16x32_bf16(
                        af[tr], bf[tc], acc[tr][tc], 0, 0, 0);
        }
    }
    #pragma unroll
    for (int tr = 0; tr < 4; tr++)
        #pragma unroll
        for (int tc = 0; tc < 4; tc++) {
            int gcol = nBase + wc * 64 + tc * 16 + col;
            float bv = bias[gcol];
            #pragma unroll
            for (int reg = 0; reg < 4; reg++) {
                int grow = mBase + wr * 64 + tr * 16 + quad * 4 + reg;
                outz[(size_t)grow * HID_N + gcol] = f2bf(acc[tr][tc][reg] + bv);
            }
        }
}

// ---------------------------------------------------------------------------
// Kernel 3: symmetric fused contrastive main. grid 528.
// ---------------------------------------------------------------------------
__global__ __launch_bounds__(256, 2) void main_fused(
    const unsigned short* __restrict__ zn, const unsigned short* __restrict__ bn,
    const unsigned short* __restrict__ f1z, const unsigned short* __restrict__ f2z,
    float* __restrict__ partials)
{
    __shared__ __align__(16) unsigned short S[4 * 128 * 64];   // 64 KB staging
    __shared__ unsigned short maskT[128 * 8];                  // 2 KB
    unsigned short* S0 = S;
    unsigned short* S1 = S + 1 * 128 * 64;
    unsigned short* S2 = S + 2 * 128 * 64;
    unsigned short* S3 = S + 3 * 128 * 64;
    unsigned short* svT = S2;   // 32 KB: sv[j][i] swizzled; overlays S2+S3

    // decode upper-triangle (ib, jc), jc >= ib
    int k = blockIdx.x, ib = 0;
    while (k >= 32 - ib) { k -= 32 - ib; ib++; }
    int jc = ib + k;
    bool diag = (ib == jc);

    int tid = threadIdx.x, lane = tid & 63, wave = tid >> 6, quad = lane >> 4, col = lane & 15;
    int wr = wave >> 1, wc = wave & 1;
    int rBase = ib * 128 + wr * 64;
    int cBase = jc * 128 + wc * 64;
    const int r8 = lane >> 3;
    const int kbl = (lane & 7) ^ r8;
    const int sw  = col & 7;

    v4f acc[4][4];

    // ================= phase M: mask GEMM (bn.bn^T), K=768 =================
    ZERO_ACC(acc);
    for (int kc = 0; kc < D_N; kc += 128) {
        __syncthreads();
        #pragma unroll
        for (int s = 0; s < 4; s++) {
            int rowbase = s * 32 + wave * 8;
            size_t rOff = (size_t)(ib * 128 + rowbase + r8) * D_N + kc + kbl * 8;
            size_t cOff = (size_t)(jc * 128 + rowbase + r8) * D_N + kc + kbl * 8;
            gld16(bn + rOff,      S0 + rowbase * 64);
            gld16(bn + cOff,      S1 + rowbase * 64);
            gld16(bn + rOff + 64, S2 + rowbase * 64);
            gld16(bn + cOff + 64, S3 + rowbase * 64);
        }
        __syncthreads();
        #pragma unroll
        for (int half = 0; half < 2; half++) {
            const unsigned short* Ax = half ? S2 : S0;
            const unsigned short* Bx = half ? S3 : S1;
            #pragma unroll
            for (int kk = 0; kk < 2; kk++) {
                int ko = (((kk << 2) + quad) ^ sw) << 3;
                v8s af[4], bf[4];
                #pragma unroll
                for (int t = 0; t < 4; t++) {
                    af[t] = *(const v8s*)(Ax + (wr * 64 + t * 16 + col) * 64 + ko);
                    bf[t] = *(const v8s*)(Bx + (wc * 64 + t * 16 + col) * 64 + ko);
                }
                #pragma unroll
                for (int tr = 0; tr < 4; tr++)
                    #pragma unroll
                    for (int tc = 0; tc < 4; tc++)
                        acc[tr][tc] = __builtin_amdgcn_mfma_f32_16x16x32_bf16(
                            af[tr], bf[tc], acc[tr][tc], 0, 0, 0);
            }
        }
    }
    unsigned long long mb = 0ull;
    #pragma unroll
    for (int tr = 0; tr < 4; tr++)
        #pragma unroll
        for (int tc = 0; tc < 4; tc++)
            #pragma unroll
            for (int reg = 0; reg < 4; reg++) {
                int grow = rBase + tr * 16 + quad * 4 + reg;
                int gcol = cBase + tc * 16 + col;
                if (acc[tr][tc][reg] > 0.05f && grow != gcol)
                    mb |= 1ull << (tr * 16 + tc * 4 + reg);
            }

    // ================= phase S: sim GEMM (zn.zn^T), K=768 ==================
    ZERO_ACC(acc);
    for (int kc = 0; kc < D_N; kc += 128) {
        __syncthreads();
        #pragma unroll
        for (int s = 0; s < 4; s++) {
            int rowbase = s * 32 + wave * 8;
            size_t rOff = (size_t)(ib * 128 + rowbase + r8) * D_N + kc + kbl * 8;
            size_t cOff = (size_t)(jc * 128 + rowbase + r8) * D_N + kc + kbl * 8;
            gld16(zn + rOff,      S0 + rowbase * 64);
            gld16(zn + cOff,      S1 + rowbase * 64);
            gld16(zn + rOff + 64, S2 + rowbase * 64);
            gld16(zn + cOff + 64, S3 + rowbase * 64);
        }
        __syncthreads();
        #pragma unroll
        for (int half = 0; half < 2; half++) {
            const unsigned short* Ax = half ? S2 : S0;
            const unsigned short* Bx = half ? S3 : S1;
            #pragma unroll
            for (int kk = 0; kk < 2; kk++) {
                int ko = (((kk << 2) + quad) ^ sw) << 3;
                v8s af[4], bf[4];
                #pragma unroll
                for (int t = 0; t < 4; t++) {
                    af[t] = *(const v8s*)(Ax + (wr * 64 + t * 16 + col) * 64 + ko);
                    bf[t] = *(const v8s*)(Bx + (wc * 64 + t * 16 + col) * 64 + ko);
                }
                #pragma unroll
                for (int tr = 0; tr < 4; tr++)
                    #pragma unroll
                    for (int tc = 0; tc < 4; tc++)
                        acc[tr][tc] = __builtin_amdgcn_mfma_f32_16x16x32_bf16(
                            af[tr], bf[tc], acc[tr][tc], 0, 0, 0);
            }
        }
    }
    // extract dsum + packed sim values; acc dies after this
    float dsum[16];
    #pragma unroll
    for (int i = 0; i < 16; i++) dsum[i] = 0.f;
    unsigned int svp[4][4][2];
    #pragma unroll
    for (int tr = 0; tr < 4; tr++)
        #pragma unroll
        for (int tc = 0; tc < 4; tc++) {
            #pragma unroll
            for (int reg = 0; reg < 4; reg++) {
                float sv = acc[tr][tc][reg];
                int grow = rBase + tr * 16 + quad * 4 + reg;
                int gcol = cBase + tc * 16 + col;
                if (grow != gcol) dsum[tr * 4 + reg] += __expf(sv * 10.0f);
            }
            svp[tr][tc][0] = ((unsigned int)f2bf(acc[tr][tc][1]) << 16) | f2bf(acc[tr][tc][0]);
            svp[tr][tc][1] = ((unsigned int)f2bf(acc[tr][tc][3]) << 16) | f2bf(acc[tr][tc][2]);
        }

    // ===== write svT (sv[j][i], 8-elem XOR swizzle) + maskT into S2/S3 =====
    __syncthreads();              // all phase-S staging reads done
    if (!diag) {
        #pragma unroll
        for (int tc = 0; tc < 4; tc++) {
            unsigned int w = 0;
            #pragma unroll
            for (int tr = 0; tr < 4; tr++)
                #pragma unroll
                for (int reg = 0; reg < 4; reg++)
                    if ((mb >> (tr * 16 + tc * 4 + reg)) & 1ull) w |= 1u << (tr * 4 + reg);
            int j = wc * 64 + tc * 16 + col;
            maskT[j * 8 + wr * 4 + quad] = (unsigned short)w;
        }
        #pragma unroll
        for (int tr = 0; tr < 4; tr++) {
            int i0 = wr * 64 + tr * 16 + quad * 4;
            #pragma unroll
            for (int tc = 0; tc < 4; tc++) {
                int j = wc * 64 + tc * 16 + col;
                int off = j * 128 + (((i0 >> 3) ^ (j & 15)) << 3) + (i0 & 7);
                uint2* p = (uint2*)(svT + off);
                p[0] = make_uint2(svp[tr][tc][0], svp[tr][tc][1]);
            }
        }
    }

    // ===== phase A1: direct attn (f1z[ib].f2z[jc]^T), K=256, S0/S1 =========
    ZERO_ACC(acc);
    for (int kc = 0; kc < HID_N; kc += 64) {
        __syncthreads();
        #pragma unroll
        for (int s = 0; s < 4; s++) {
            int rowbase = s * 32 + wave * 8;
            gld16(f1z + (size_t)(ib * 128 + rowbase + r8) * HID_N + kc + kbl * 8,
                  S0 + rowbase * 64);
            gld16(f2z + (size_t)(jc * 128 + rowbase + r8) * HID_N + kc + kbl * 8,
                  S1 + rowbase * 64);
        }
        __syncthreads();
        #pragma unroll
        for (int kk = 0; kk < 2; kk++) {
            int ko = (((kk << 2) + quad) ^ sw) << 3;
            v8s af[4], bf[4];
            #pragma unroll
            for (int t = 0; t < 4; t++) {
                af[t] = *(const v8s*)(S0 + (wr * 64 + t * 16 + col) * 64 + ko);
                bf[t] = *(const v8s*)(S1 + (wc * 64 + t * 16 + col) * 64 + ko);
            }
            #pragma unroll
            for (int tr = 0; tr < 4; tr++)
                #pragma unroll
                for (int tc = 0; tc < 4; tc++)
                    acc[tr][tc] = __builtin_amdgcn_mfma_f32_16x16x32_bf16(
                        af[tr], bf[tc], acc[tr][tc], 0, 0, 0);
        }
    }
    // direct combine (rows ib, chunk jc*2+wc); svp/dsum/mb die here
    #pragma unroll
    for (int tr = 0; tr < 4; tr++)
        #pragma unroll
        for (int reg = 0; reg < 4; reg++) {
            float lsum = 0.f, asum = 0.f, nnf = 0.f;
            float ds = dsum[tr * 4 + reg];
            int grow = rBase + tr * 16 + quad * 4 + reg;
            #pragma unroll
            for (int tc = 0; tc < 4; tc++) {
                if ((mb >> (tr * 16 + tc * 4 + reg)) & 1ull) {
                    unsigned int pk = svp[tr][tc][reg >> 1];
                    float sv = bf2f((unsigned short)((reg & 1) ? (pk >> 16) : (pk & 0xFFFF)));
                    float e = __expf(acc[tr][tc][reg]);
                    lsum += e; asum += e * sv; nnf += 1.f;
                }
            }
            #pragma unroll
            for (int m = 1; m < 16; m <<= 1) {
                lsum += __shfl_xor(lsum, m); asum += __shfl_xor(asum, m);
                ds   += __shfl_xor(ds, m);   nnf  += __shfl_xor(nnf, m);
            }
            if (col == 0) {
                float4 v; v.x = lsum; v.y = asum; v.z = ds; v.w = nnf;
                *(float4*)(partials + ((size_t)grow * 64 + jc * 2 + wc) * 4) = v;
            }
        }

    if (diag) return;

    // ===== phase A2: transposed attn (f1z[jc].f2z[ib]^T), K=256 ============
    ZERO_ACC(acc);
    for (int kc = 0; kc < HID_N; kc += 64) {
        __syncthreads();
        #pragma unroll
        for (int s = 0; s < 4; s++) {
            int rowbase = s * 32 + wave * 8;
            gld16(f1z + (size_t)(jc * 128 + rowbase + r8) * HID_N + kc + kbl * 8,
                  S0 + rowbase * 64);
            gld16(f2z + (size_t)(ib * 128 + rowbase + r8) * HID_N + kc + kbl * 8,
                  S1 + rowbase * 64);
        }
        __syncthreads();
        #pragma unroll
        for (int kk = 0; kk < 2; kk++) {
            int ko = (((kk << 2) + quad) ^ sw) << 3;
            v8s af[4], bf[4];
            #pragma unroll
            for (int t = 0; t < 4; t++) {
                af[t] = *(const v8s*)(S0 + (wr * 64 + t * 16 + col) * 64 + ko);
                bf[t] = *(const v8s*)(S1 + (wc * 64 + t * 16 + col) * 64 + ko);
            }
            #pragma unroll
            for (int tr = 0; tr < 4; tr++)
                #pragma unroll
                for (int tc = 0; tc < 4; tc++)
                    acc[tr][tc] = __builtin_amdgcn_mfma_f32_16x16x32_bf16(
                        af[tr], bf[tc], acc[tr][tc], 0, 0, 0);
        }
    }
    // transposed combine (rows jc, chunk ib*2+wc) from svT/maskT
    #pragma unroll
    for (int tr = 0; tr < 4; tr++)
        #pragma unroll
        for (int reg = 0; reg < 4; reg++) {
            float lsum = 0.f, asum = 0.f, ds = 0.f, nnf = 0.f;
            int jl = wr * 64 + tr * 16 + quad * 4 + reg;      // local j
            unsigned int mwv = maskT[jl * 8 + wc * 4 + (col >> 2)];
            unsigned int mybit = 1u << (col & 3);
            #pragma unroll
            for (int tc = 0; tc < 4; tc++) {
                int il = wc * 64 + tc * 16 + col;
                float sv = bf2f(svT[jl * 128 + (((il >> 3) ^ (jl & 15)) << 3) + (il & 7)]);
                ds += __expf(sv * 10.0f);
                if (mwv & (mybit << (tc * 4))) {
                    float e = __expf(acc[tr][tc][reg]);
                    lsum += e; asum += e * sv; nnf += 1.f;
                }
            }
            #pragma unroll
            for (int m = 1; m < 16; m <<= 1) {
                lsum += __shfl_xor(lsum, m); asum += __shfl_xor(asum, m);
                ds   += __shfl_xor(ds, m);   nnf  += __shfl_xor(nnf, m);
            }
            if (col == 0) {
                int row = jc * 128 + jl;
                float4 v; v.x = lsum; v.y = asum; v.z = ds; v.w = nnf;
                *(float4*)(partials + ((size_t)row * 64 + ib * 2 + wc) * 4) = v;
            }
        }
}

// ---------------------------------------------------------------------------
// Kernel 4: reduce per-row partials; last block does entropy + combine.
// ---------------------------------------------------------------------------
__global__ __launch_bounds__(256) void row_reduce_fin(
    const float* __restrict__ partials, const float* __restrict__ mpart,
    float* __restrict__ acc, float* __restrict__ out)
{
    int tid = threadIdx.x;
    int row = blockIdx.x * 64 + (tid >> 2);
    int sub = tid & 3;
    const float4* p = (const float4*)partials + (size_t)row * 64 + sub * 16;
    float L = 0.f, A = 0.f, Dn = 0.f, NN = 0.f;
    #pragma unroll
    for (int c = 0; c < 16; c++) { float4 v = p[c]; L += v.x; A += v.y; Dn += v.z; NN += v.w; }
    #pragma unroll
    for (int m = 1; m < 4; m <<= 1) {
        L += __shfl_xor(L, m); A += __shfl_xor(A, m);
        Dn += __shfl_xor(Dn, m); NN += __shfl_xor(NN, m);
    }
    float per = 0.f, val = 0.f;
    if (sub == 0 && NN > 0.5f) {
        per = (logf(Dn + 1e-8f) - 10.0f * (A / L)) / NN;
        val = 1.0f;
    }
    __shared__ float red[256];
    __shared__ float r2s[256];
    __shared__ int amLast;
    red[tid] = per; r2s[tid] = val; __syncthreads();
    for (int s = 128; s > 0; s >>= 1) {
        if (tid < s) { red[tid] += red[tid + s]; r2s[tid] += r2s[tid + s]; }
        __syncthreads();
    }
    if (tid == 0) {
        atomicAdd(&acc[0], red[0]);
        atomicAdd(&acc[1], r2s[0]);
        __threadfence();
        int old = atomicAdd((int*)&acc[2], 1);
        amLast = (old == (int)gridDim.x - 1);
    }
    __syncthreads();
    if (!amLast) return;

    __shared__ float bcast[2];
    float pcl = 0.0f;
    if (tid < NCLS) {
        const float4* mp = (const float4*)(mpart + (size_t)tid * 256);
        float s = 0.f;
        #pragma unroll
        for (int c = 0; c < 64; c++) { float4 v = mp[c]; s += v.x + v.y + v.z + v.w; }
        pcl = s * (1.0f / 4096.0f);
    }
    red[tid] = (tid < 100) ? pcl : 0.0f; __syncthreads();
    for (int s = 128; s > 0; s >>= 1) { if (tid < s) red[tid] += red[tid + s]; __syncthreads(); }
    if (tid == 0) bcast[0] = red[0];
    __syncthreads();
    red[tid] = (tid >= 100 && tid < NCLS) ? pcl : 0.0f; __syncthreads();
    for (int s = 128; s > 0; s >>= 1) { if (tid < s) red[tid] += red[tid + s]; __syncthreads(); }
    if (tid == 0) bcast[1] = red[0];
    __syncthreads();
    float p_old = bcast[0], p_new = bcast[1];

    float t = 0.0f;
    if (tid < 100)       { float q = pcl / (p_old + 1e-8f); t = q * logf(q + 1e-8f); }
    else if (tid < NCLS) { float q = pcl / (p_new + 1e-8f); t = q * logf(q + 1e-8f); }
    red[tid] = t; __syncthreads();
    for (int s = 128; s > 0; s >>= 1) { if (tid < s) red[tid] += red[tid + s]; __syncthreads(); }

    if (tid == 0) {
        float s0 = __hip_atomic_load(&acc[0], __ATOMIC_RELAXED, __HIP_MEMORY_SCOPE_AGENT);
        float s1 = __hip_atomic_load(&acc[1], __ATOMIC_RELAXED, __HIP_MEMORY_SCOPE_AGENT);
        float loss_inter = p_old * logf(p_old + 1e-8f) + p_new * logf(p_new + 1e-8f)
                           + 0.69314718056f;
        float loss_entropy = loss_inter + red[0] + 2.0f * 4.60517018599f;
        float lc = (s1 > 0.5f) ? s0 / s1 : 0.0f;
        out[0] = loss_entropy + lc;
    }
}

// ---------------------------------------------------------------------------
extern "C" void kernel_launch(void* const* d_in, const int* in_sizes, int n_in,
                              void* d_out, int out_size, void* d_ws, size_t ws_size,
                              hipStream_t stream)
{
    const float* z_u    = (const float*)d_in[0];
    const float* logits = (const float*)d_in[1];
    const int*   oldi   = (const int*)d_in[2];
    const int*   newi   = (const int*)d_in[3];
    const float* basef  = (const float*)d_in[4];
    const float* f1w    = (const float*)d_in[5];
    const float* f1b    = (const float*)d_in[6];
    const float* f2w    = (const float*)d_in[7];
    const float* f2b    = (const float*)d_in[8];
    float* out = (float*)d_out;

    unsigned short* zn   = (unsigned short*)d_ws;          // [B][D] bf16
    unsigned short* bn   = zn  + (size_t)B_N * D_N;
    unsigned short* f1z  = bn  + (size_t)B_N * D_N;        // [B][HID]
    unsigned short* f2z  = f1z + (size_t)B_N * HID_N;
    float* partials = (float*)(f2z + (size_t)B_N * HID_N); // [B][64][4]
    float* mpart    = partials + (size_t)B_N * 64 * 4;     // [256 class][256 blk]
    float* accums   = mpart + 256 * 256;                   // [2] + counter

    pre_all<<<B_N + 256, 256, 0, stream>>>(z_u, basef, logits, oldi, newi,
                                           zn, bn, mpart, accums);
    fz_gemm<<<dim3(B_N / 128, 4), 256, 0, stream>>>(z_u, f1w, f2w, f1b, f2b, f1z, f2z);
    main_fused<<<528, 256, 0, stream>>>(zn, bn, f1z, f2z, partials);
    row_reduce_fin<<<64, 256, 0, stream>>>(partials, mpart, accums, out);
}

// Round 9
// 203.075 us; speedup vs baseline: 1.3608x; 1.3608x over previous
//
#include <hip/hip_runtime.h>

// ---------------------------------------------------------------------------
// Debiased Representation Loss — fused MI355X implementation (R9 = R4 revert).
// R4 is the measured-best configuration (205 us total, main_fused 77 us,
// WRITE 4 MB, 0 LDS conflicts). R5-R8 symmetric variants all regressed
// (persistent ~18 MB scratch spill + 528-block quantization). This file is
// the R4 source re-established as baseline.
// Heavy part: three pairwise 4096x4096 matrices (mask K=768, sim K=768,
// attn K=256); mask+sim GEMMs share ONE K-loop (half the barriers), attn
// K=256 at 128-K per barrier-pair; atomic-free softmax partials.
// ---------------------------------------------------------------------------

#define B_N   4096
#define D_N   768
#define HID_N 256
#define NCLS  200

typedef __attribute__((ext_vector_type(8))) short v8s;   // 8 x bf16 (4 VGPRs)
typedef __attribute__((ext_vector_type(4))) float v4f;   // MFMA accumulator

// round-to-nearest-even fp32 -> bf16
__device__ __forceinline__ unsigned short f2bf(float x) {
    unsigned int u = __float_as_uint(x);
    unsigned int r = (u + 0x7FFFu + ((u >> 16) & 1u)) >> 16;
    return (unsigned short)r;
}
__device__ __forceinline__ float bf2f(unsigned short h) {
    return __uint_as_float((unsigned int)h << 16);
}

// async global->LDS, 16 B per lane; lane i lands at ldsbase + i*16
__device__ __forceinline__ void gld16(const unsigned short* g, unsigned short* l) {
    __builtin_amdgcn_global_load_lds(
        (__attribute__((address_space(1))) void*)g,
        (__attribute__((address_space(3))) void*)l, 16, 0, 0);
}

#define ZERO_ACC(a) { _Pragma("unroll") for (int _i = 0; _i < 4; _i++) \
    _Pragma("unroll") for (int _j = 0; _j < 4; _j++) a[_i][_j] = (v4f){0.f,0.f,0.f,0.f}; }

// ---------------------------------------------------------------------------
// Kernel 1: L2-normalize z_u and base_features rows; emit bf16 copies.
// Blocks >= 4096 convert f1_w / f2_w to bf16 instead.
// ---------------------------------------------------------------------------
__global__ __launch_bounds__(256) void normalize_k(
    const float* __restrict__ z, const float* __restrict__ base,
    const float* __restrict__ w1, const float* __restrict__ w2,
    unsigned short* __restrict__ zn, unsigned short* __restrict__ bn,
    unsigned short* __restrict__ zb,
    unsigned short* __restrict__ o1, unsigned short* __restrict__ o2)
{
    int tid = threadIdx.x;
    if (blockIdx.x >= B_N) {                     // weight conversion tail
        int b2 = blockIdx.x - B_N;               // 0..7
        const float* src = (b2 < 4) ? w1 : w2;
        unsigned short* dst = (b2 < 4) ? o1 : o2;
        int base2 = (b2 & 3) * 49152 + tid;      // 196608/4 per block
        #pragma unroll 4
        for (int i = 0; i < 192; i++) dst[base2 + i * 256] = f2bf(src[base2 + i * 256]);
        return;
    }
    int row = blockIdx.x;
    __shared__ float ws1[4], ws2[4];
    const float* zr = z    + (size_t)row * D_N;
    const float* br = base + (size_t)row * D_N;
    float z0 = zr[tid], z1 = zr[tid + 256], z2 = zr[tid + 512];
    float b0 = br[tid], b1 = br[tid + 256], b2 = br[tid + 512];
    float s1 = z0*z0 + z1*z1 + z2*z2;
    float s2 = b0*b0 + b1*b1 + b2*b2;
    #pragma unroll
    for (int m = 32; m > 0; m >>= 1) { s1 += __shfl_xor(s1, m); s2 += __shfl_xor(s2, m); }
    if ((tid & 63) == 0) { ws1[tid >> 6] = s1; ws2[tid >> 6] = s2; }
    __syncthreads();
    float t1 = ws1[0] + ws1[1] + ws1[2] + ws1[3];
    float t2 = ws2[0] + ws2[1] + ws2[2] + ws2[3];
    float sc1 = 1.0f / fmaxf(sqrtf(t1), 1e-12f);
    float sc2 = 1.0f / fmaxf(sqrtf(t2), 1e-12f);
    size_t o = (size_t)row * D_N;
    zn[o+tid] = f2bf(z0*sc1); zn[o+tid+256] = f2bf(z1*sc1); zn[o+tid+512] = f2bf(z2*sc1);
    bn[o+tid] = f2bf(b0*sc2); bn[o+tid+256] = f2bf(b1*sc2); bn[o+tid+512] = f2bf(b2*sc2);
    zb[o+tid] = f2bf(z0);     zb[o+tid+256] = f2bf(z1);     zb[o+tid+512] = f2bf(z2);
}

// ---------------------------------------------------------------------------
// Shared mini-GEMM: block tile 128x128, NT bf16; 2x2 wave grid, 4x4 MFMA
// tiles per wave. global_load_lds width-16 staging, XOR-swizzled unpadded
// LDS rows (stride 64 ushorts): physical kblock = logical ^ (row & 7).
// (0 bank conflicts measured R2-R4.)  Used by fz_gemm only.
// ---------------------------------------------------------------------------
__device__ __forceinline__ void mm_tile128(
    const unsigned short* __restrict__ Ag, const unsigned short* __restrict__ Bg,
    int aRow0, int bRow0, int K,
    unsigned short* Al, unsigned short* Bl, v4f acc[4][4])
{
    const int tid = threadIdx.x;
    const int lane = tid & 63, wave = tid >> 6, quad = lane >> 4, col = lane & 15;
    const int wr = wave >> 1, wc = wave & 1;
    const int r8 = lane >> 3;
    const int kbl = (lane & 7) ^ r8;
    const int sw  = col & 7;
    for (int kc = 0; kc < K; kc += 64) {
        __syncthreads();
        #pragma unroll
        for (int s = 0; s < 4; s++) {
            int rowbase = s * 32 + wave * 8;
            gld16(Ag + (size_t)(aRow0 + rowbase + r8) * K + kc + kbl * 8,
                  Al + rowbase * 64);
            gld16(Bg + (size_t)(bRow0 + rowbase + r8) * K + kc + kbl * 8,
                  Bl + rowbase * 64);
        }
        __syncthreads();
        #pragma unroll
        for (int kk = 0; kk < 2; kk++) {
            int ko = (((kk << 2) + quad) ^ sw) << 3;
            v8s af[4], bf[4];
            #pragma unroll
            for (int t = 0; t < 4; t++) {
                af[t] = *(const v8s*)(Al + (wr * 64 + t * 16 + col) * 64 + ko);
                bf[t] = *(const v8s*)(Bl + (wc * 64 + t * 16 + col) * 64 + ko);
            }
            #pragma unroll
            for (int tr = 0; tr < 4; tr++)
                #pragma unroll
                for (int tc = 0; tc < 4; tc++)
                    acc[tr][tc] = __builtin_amdgcn_mfma_f32_16x16x32_bf16(
                        af[tr], bf[tc], acc[tr][tc], 0, 0, 0);
        }
    }
}

// ---------------------------------------------------------------------------
// Kernel 2: fz = z @ W^T + b for BOTH weights in one launch. grid (32, 4).
// ---------------------------------------------------------------------------
__global__ __launch_bounds__(256, 2) void fz_gemm(
    const unsigned short* __restrict__ zb,
    const unsigned short* __restrict__ w1b, const unsigned short* __restrict__ w2b,
    const float* __restrict__ b1, const float* __restrict__ b2,
    unsigned short* __restrict__ f1z, unsigned short* __restrict__ f2z)
{
    __shared__ __align__(16) unsigned short Al[128 * 64];
    __shared__ __align__(16) unsigned short Bl[128 * 64];
    int which = blockIdx.y >> 1;
    const unsigned short* wb = which ? w2b : w1b;
    const float* bias = which ? b2 : b1;
    unsigned short* outz = which ? f2z : f1z;
    int mBase = blockIdx.x * 128, nBase = (blockIdx.y & 1) * 128;
    v4f acc[4][4]; ZERO_ACC(acc);
    mm_tile128(zb, wb, mBase, nBase, D_N, Al, Bl, acc);
    int tid = threadIdx.x, lane = tid & 63, wave = tid >> 6, quad = lane >> 4, col = lane & 15;
    int wr = wave >> 1, wc = wave & 1;
    #pragma unroll
    for (int tr = 0; tr < 4; tr++)
        #pragma unroll
        for (int tc = 0; tc < 4; tc++) {
            int gcol = nBase + wc * 64 + tc * 16 + col;
            float bv = bias[gcol];
            #pragma unroll
            for (int reg = 0; reg < 4; reg++) {
                int grow = mBase + wr * 64 + tr * 16 + quad * 4 + reg;
                outz[(size_t)grow * HID_N + gcol] = f2bf(acc[tr][tc][reg] + bv);
            }
        }
}

// ---------------------------------------------------------------------------
// Kernel 3: per-row softmax over gathered logits; ATOMIC-FREE: each block
// writes its per-class partial sum to mpart[class*256 + block].
// grid 256 blocks x 16 rows.
// ---------------------------------------------------------------------------
__global__ __launch_bounds__(256) void softmax_mean(
    const float* __restrict__ logits, const int* __restrict__ oldi,
    const int* __restrict__ newi, float* __restrict__ mpart)
{
    __shared__ int act[256];
    __shared__ float accs[4][256];
    int tid = threadIdx.x, lane = tid & 63, wave = tid >> 6;
    if (tid < NCLS) act[tid] = (tid < 100) ? oldi[tid] : newi[tid - 100];
    accs[0][tid] = 0.f; accs[1][tid] = 0.f; accs[2][tid] = 0.f; accs[3][tid] = 0.f;
    __syncthreads();
    int a0 = act[lane], a1 = act[lane + 64], a2 = act[lane + 128];
    int a3 = (lane < 8) ? act[lane + 192] : 0;
    int r0 = blockIdx.x * 16 + wave * 4;
    float c0 = 0.f, c1 = 0.f, c2 = 0.f, c3 = 0.f;
    for (int i = 0; i < 4; i++) {
        const float* lr = logits + (size_t)(r0 + i) * NCLS;
        float x0 = lr[a0], x1 = lr[a1], x2 = lr[a2];
        float x3 = (lane < 8) ? lr[a3] : -3.0e38f;
        float m = fmaxf(fmaxf(x0, x1), fmaxf(x2, x3));
        #pragma unroll
        for (int s = 32; s > 0; s >>= 1) m = fmaxf(m, __shfl_xor(m, s));
        float e0 = __expf(x0 - m), e1 = __expf(x1 - m), e2 = __expf(x2 - m);
        float e3 = (lane < 8) ? __expf(x3 - m) : 0.f;
        float sm = e0 + e1 + e2 + e3;
        #pragma unroll
        for (int s = 32; s > 0; s >>= 1) sm += __shfl_xor(sm, s);
        float inv = 1.0f / sm;
        c0 += e0 * inv; c1 += e1 * inv; c2 += e2 * inv; c3 += e3 * inv;
    }
    accs[wave][lane] = c0; accs[wave][lane + 64] = c1; accs[wave][lane + 128] = c2;
    if (lane < 8) accs[wave][lane + 192] = c3;
    __syncthreads();
    mpart[(size_t)tid * 256 + blockIdx.x] =
        accs[0][tid] + accs[1][tid] + accs[2][tid] + accs[3][tid];
}

// ---------------------------------------------------------------------------
// Kernel 4: fused contrastive main. grid (32, 32); block = 128x128 tile.
// mask (bn.bn^T) and sim (zn.zn^T) GEMMs share ONE K=768 loop with 4 LDS
// buffers -> half the barriers for 2/3 of the FLOPs; attn phase (K=256) does
// 128-K per barrier-pair. 2x2 wave grid; partial chunk = jc*2 + wc.
// ---------------------------------------------------------------------------
__global__ __launch_bounds__(256, 2) void main_fused(
    const unsigned short* __restrict__ zn, const unsigned short* __restrict__ bn,
    const unsigned short* __restrict__ f1z, const unsigned short* __restrict__ f2z,
    float* __restrict__ partials)
{
    __shared__ __align__(16) unsigned short A1[128 * 64];
    __shared__ __align__(16) unsigned short B1[128 * 64];
    __shared__ __align__(16) unsigned short A2[128 * 64];
    __shared__ __align__(16) unsigned short B2[128 * 64];
    int tid = threadIdx.x, lane = tid & 63, wave = tid >> 6, quad = lane >> 4, col = lane & 15;
    int wr = wave >> 1, wc = wave & 1;
    int ib = blockIdx.x, jc = blockIdx.y;
    int rBase = ib * 128 + wr * 64;
    int cBase = jc * 128 + wc * 64;
    const int r8 = lane >> 3;
    const int kbl = (lane & 7) ^ r8;
    const int sw  = col & 7;

    // --- fused phase 1+2: mask GEMM (accB) + sim GEMM (accS), K = 768 ---
    v4f accB[4][4], accS[4][4];
    ZERO_ACC(accB); ZERO_ACC(accS);
    for (int kc = 0; kc < D_N; kc += 64) {
        __syncthreads();
        #pragma unroll
        for (int s = 0; s < 4; s++) {
            int rowbase = s * 32 + wave * 8;
            size_t rOff = (size_t)(ib * 128 + rowbase + r8) * D_N + kc + kbl * 8;
            size_t cOff = (size_t)(jc * 128 + rowbase + r8) * D_N + kc + kbl * 8;
            gld16(bn + rOff, A1 + rowbase * 64);
            gld16(bn + cOff, B1 + rowbase * 64);
            gld16(zn + rOff, A2 + rowbase * 64);
            gld16(zn + cOff, B2 + rowbase * 64);
        }
        __syncthreads();
        #pragma unroll
        for (int kk = 0; kk < 2; kk++) {
            int ko = (((kk << 2) + quad) ^ sw) << 3;
            v8s a1[4], b1[4], a2[4], b2[4];
            #pragma unroll
            for (int t = 0; t < 4; t++) {
                a1[t] = *(const v8s*)(A1 + (wr * 64 + t * 16 + col) * 64 + ko);
                b1[t] = *(const v8s*)(B1 + (wc * 64 + t * 16 + col) * 64 + ko);
                a2[t] = *(const v8s*)(A2 + (wr * 64 + t * 16 + col) * 64 + ko);
                b2[t] = *(const v8s*)(B2 + (wc * 64 + t * 16 + col) * 64 + ko);
            }
            #pragma unroll
            for (int tr = 0; tr < 4; tr++)
                #pragma unroll
                for (int tc = 0; tc < 4; tc++) {
                    accB[tr][tc] = __builtin_amdgcn_mfma_f32_16x16x32_bf16(
                        a1[tr], b1[tc], accB[tr][tc], 0, 0, 0);
                    accS[tr][tc] = __builtin_amdgcn_mfma_f32_16x16x32_bf16(
                        a2[tr], b2[tc], accS[tr][tc], 0, 0, 0);
                }
        }
    }

    // mask bits from accB
    unsigned long long mb = 0ull;
    #pragma unroll
    for (int tr = 0; tr < 4; tr++)
        #pragma unroll
        for (int tc = 0; tc < 4; tc++)
            #pragma unroll
            for (int reg = 0; reg < 4; reg++) {
                int grow = rBase + tr * 16 + quad * 4 + reg;
                int gcol = cBase + tc * 16 + col;
                if (accB[tr][tc][reg] > 0.05f && grow != gcol)
                    mb |= 1ull << (tr * 16 + tc * 4 + reg);
            }

    // dsum + packed bf16 sim values from accS
    float dsum[16];
    #pragma unroll
    for (int i = 0; i < 16; i++) dsum[i] = 0.f;
    unsigned int svp[4][4][2];
    #pragma unroll
    for (int tr = 0; tr < 4; tr++)
        #pragma unroll
        for (int tc = 0; tc < 4; tc++) {
            #pragma unroll
            for (int reg = 0; reg < 4; reg++) {
                float sv = accS[tr][tc][reg];
                int grow = rBase + tr * 16 + quad * 4 + reg;
                int gcol = cBase + tc * 16 + col;
                if (grow != gcol) dsum[tr * 4 + reg] += __expf(sv * 10.0f);
            }
            svp[tr][tc][0] = ((unsigned int)f2bf(accS[tr][tc][1]) << 16) | f2bf(accS[tr][tc][0]);
            svp[tr][tc][1] = ((unsigned int)f2bf(accS[tr][tc][3]) << 16) | f2bf(accS[tr][tc][2]);
        }

    // --- phase 3: attn GEMM (K=256), 128-K per barrier-pair ---
    v4f accA[4][4]; ZERO_ACC(accA);
    for (int kc = 0; kc < HID_N; kc += 128) {
        __syncthreads();
        #pragma unroll
        for (int s = 0; s < 4; s++) {
            int rowbase = s * 32 + wave * 8;
            size_t rOff = (size_t)(ib * 128 + rowbase + r8) * HID_N + kc + kbl * 8;
            size_t cOff = (size_t)(jc * 128 + rowbase + r8) * HID_N + kc + kbl * 8;
            gld16(f1z + rOff,      A1 + rowbase * 64);
            gld16(f2z + cOff,      B1 + rowbase * 64);
            gld16(f1z + rOff + 64, A2 + rowbase * 64);
            gld16(f2z + cOff + 64, B2 + rowbase * 64);
        }
        __syncthreads();
        #pragma unroll
        for (int half = 0; half < 2; half++) {
            const unsigned short* Ax = half ? A2 : A1;
            const unsigned short* Bx = half ? B2 : B1;
            #pragma unroll
            for (int kk = 0; kk < 2; kk++) {
                int ko = (((kk << 2) + quad) ^ sw) << 3;
                v8s af[4], bf[4];
                #pragma unroll
                for (int t = 0; t < 4; t++) {
                    af[t] = *(const v8s*)(Ax + (wr * 64 + t * 16 + col) * 64 + ko);
                    bf[t] = *(const v8s*)(Bx + (wc * 64 + t * 16 + col) * 64 + ko);
                }
                #pragma unroll
                for (int tr = 0; tr < 4; tr++)
                    #pragma unroll
                    for (int tc = 0; tc < 4; tc++)
                        accA[tr][tc] = __builtin_amdgcn_mfma_f32_16x16x32_bf16(
                            af[tr], bf[tc], accA[tr][tc], 0, 0, 0);
            }
        }
    }

    // --- combine ---
    float lsum[16], asum[16], nnf[16];
    #pragma unroll
    for (int i = 0; i < 16; i++) { lsum[i] = 0.f; asum[i] = 0.f; nnf[i] = 0.f; }
    #pragma unroll
    for (int tr = 0; tr < 4; tr++)
        #pragma unroll
        for (int tc = 0; tc < 4; tc++)
            #pragma unroll
            for (int reg = 0; reg < 4; reg++) {
                if ((mb >> (tr * 16 + tc * 4 + reg)) & 1ull) {
                    int slot = tr * 4 + reg;
                    float e = __expf(accA[tr][tc][reg]);
                    unsigned int pk = svp[tr][tc][reg >> 1];
                    float sv = bf2f((unsigned short)((reg & 1) ? (pk >> 16) : (pk & 0xFFFF)));
                    lsum[slot] += e;
                    asum[slot] += e * sv;
                    nnf[slot] += 1.f;
                }
            }

    #pragma unroll
    for (int i = 0; i < 16; i++) {
        #pragma unroll
        for (int m = 1; m < 16; m <<= 1) {
            lsum[i] += __shfl_xor(lsum[i], m);
            asum[i] += __shfl_xor(asum[i], m);
            dsum[i] += __shfl_xor(dsum[i], m);
            nnf[i]  += __shfl_xor(nnf[i], m);
        }
        if (col == 0) {
            int row = rBase + (i >> 2) * 16 + quad * 4 + (i & 3);
            float4 v; v.x = lsum[i]; v.y = asum[i]; v.z = dsum[i]; v.w = nnf[i];
            *(float4*)(partials + ((size_t)row * 64 + jc * 2 + wc) * 4) = v;
        }
    }
}

// ---------------------------------------------------------------------------
// Kernel 5: reduce per-row partials (64 blocks, 4 lanes/row); last block
// computes entropy term from mpart + final combine -> d_out[0].
// ---------------------------------------------------------------------------
__global__ __launch_bounds__(256) void row_reduce_fin(
    const float* __restrict__ partials, const float* __restrict__ mpart,
    float* __restrict__ acc, float* __restrict__ out)
{
    int tid = threadIdx.x;
    int row = blockIdx.x * 64 + (tid >> 2);
    int sub = tid & 3;
    const float4* p = (const float4*)partials + (size_t)row * 64 + sub * 16;
    float L = 0.f, A = 0.f, Dn = 0.f, NN = 0.f;
    #pragma unroll
    for (int c = 0; c < 16; c++) { float4 v = p[c]; L += v.x; A += v.y; Dn += v.z; NN += v.w; }
    #pragma unroll
    for (int m = 1; m < 4; m <<= 1) {
        L += __shfl_xor(L, m); A += __shfl_xor(A, m);
        Dn += __shfl_xor(Dn, m); NN += __shfl_xor(NN, m);
    }
    float per = 0.f, val = 0.f;
    if (sub == 0 && NN > 0.5f) {
        per = (logf(Dn + 1e-8f) - 10.0f * (A / L)) / NN;
        val = 1.0f;
    }
    __shared__ float red[256];
    __shared__ float r2s[256];
    __shared__ int amLast;
    red[tid] = per; r2s[tid] = val; __syncthreads();
    for (int s = 128; s > 0; s >>= 1) {
        if (tid < s) { red[tid] += red[tid + s]; r2s[tid] += r2s[tid + s]; }
        __syncthreads();
    }
    if (tid == 0) {
        atomicAdd(&acc[0], red[0]);
        atomicAdd(&acc[1], r2s[0]);
        __threadfence();
        int old = atomicAdd((int*)&acc[2], 1);
        amLast = (old == (int)gridDim.x - 1);
    }
    __syncthreads();
    if (!amLast) return;

    // ---- final block: entropy + combine ----
    __shared__ float bcast[2];
    float pcl = 0.0f;
    if (tid < NCLS) {
        const float4* mp = (const float4*)(mpart + (size_t)tid * 256);
        float s = 0.f;
        #pragma unroll
        for (int c = 0; c < 64; c++) { float4 v = mp[c]; s += v.x + v.y + v.z + v.w; }
        pcl = s * (1.0f / 4096.0f);
    }
    red[tid] = (tid < 100) ? pcl : 0.0f; __syncthreads();
    for (int s = 128; s > 0; s >>= 1) { if (tid < s) red[tid] += red[tid + s]; __syncthreads(); }
    if (tid == 0) bcast[0] = red[0];
    __syncthreads();
    red[tid] = (tid >= 100 && tid < NCLS) ? pcl : 0.0f; __syncthreads();
    for (int s = 128; s > 0; s >>= 1) { if (tid < s) red[tid] += red[tid + s]; __syncthreads(); }
    if (tid == 0) bcast[1] = red[0];
    __syncthreads();
    float p_old = bcast[0], p_new = bcast[1];

    float t = 0.0f;
    if (tid < 100)       { float q = pcl / (p_old + 1e-8f); t = q * logf(q + 1e-8f); }
    else if (tid < NCLS) { float q = pcl / (p_new + 1e-8f); t = q * logf(q + 1e-8f); }
    red[tid] = t; __syncthreads();
    for (int s = 128; s > 0; s >>= 1) { if (tid < s) red[tid] += red[tid + s]; __syncthreads(); }

    if (tid == 0) {
        float s0 = __hip_atomic_load(&acc[0], __ATOMIC_RELAXED, __HIP_MEMORY_SCOPE_AGENT);
        float s1 = __hip_atomic_load(&acc[1], __ATOMIC_RELAXED, __HIP_MEMORY_SCOPE_AGENT);
        float loss_inter = p_old * logf(p_old + 1e-8f) + p_new * logf(p_new + 1e-8f)
                           + 0.69314718056f;
        float loss_entropy = loss_inter + red[0] + 2.0f * 4.60517018599f;
        float lc = (s1 > 0.5f) ? s0 / s1 : 0.0f;
        out[0] = loss_entropy + lc;
    }
}

// ---------------------------------------------------------------------------
extern "C" void kernel_launch(void* const* d_in, const int* in_sizes, int n_in,
                              void* d_out, int out_size, void* d_ws, size_t ws_size,
                              hipStream_t stream)
{
    const float* z_u    = (const float*)d_in[0];
    const float* logits = (const float*)d_in[1];
    const int*   oldi   = (const int*)d_in[2];
    const int*   newi   = (const int*)d_in[3];
    const float* basef  = (const float*)d_in[4];
    const float* f1w    = (const float*)d_in[5];
    const float* f1b    = (const float*)d_in[6];
    const float* f2w    = (const float*)d_in[7];
    const float* f2b    = (const float*)d_in[8];
    float* out = (float*)d_out;

    unsigned short* zn   = (unsigned short*)d_ws;          // [B][D] bf16
    unsigned short* bn   = zn  + (size_t)B_N * D_N;
    unsigned short* zb   = bn  + (size_t)B_N * D_N;
    unsigned short* w1b  = zb  + (size_t)B_N * D_N;        // [HID][D]
    unsigned short* w2b  = w1b + (size_t)HID_N * D_N;
    unsigned short* f1z  = w2b + (size_t)HID_N * D_N;      // [B][HID]
    unsigned short* f2z  = f1z + (size_t)B_N * HID_N;
    float* partials = (float*)(f2z + (size_t)B_N * HID_N); // [B][64][4]
    float* mpart    = partials + (size_t)B_N * 64 * 4;     // [256 class][256 blk]
    float* accums   = mpart + 256 * 256;                   // [2] + counter

    hipMemsetAsync(accums, 0, 4 * sizeof(float), stream);

    normalize_k<<<B_N + 8, 256, 0, stream>>>(z_u, basef, f1w, f2w, zn, bn, zb, w1b, w2b);
    fz_gemm<<<dim3(B_N / 128, 4), 256, 0, stream>>>(zb, w1b, w2b, f1b, f2b, f1z, f2z);
    softmax_mean<<<256, 256, 0, stream>>>(logits, oldi, newi, mpart);
    main_fused<<<dim3(32, 32), 256, 0, stream>>>(zn, bn, f1z, f2z, partials);
    row_reduce_fin<<<64, 256, 0, stream>>>(partials, mpart, accums, out);
}

// Round 10
// 196.342 us; speedup vs baseline: 1.4075x; 1.0343x over previous
//
#include <hip/hip_runtime.h>
#include <hip/hip_fp8.h>

// ---------------------------------------------------------------------------
// Debiased Representation Loss — fused MI355X implementation (R10).
// R4/R9 structure (measured best: main 76.5us, 0 conflicts, no spill) with
// fp8-e4m3 staging for all three pairwise GEMMs (half the LDS/HBM bytes,
// same MFMA rate):
//   MS : mask(bn8)+sim(zn8) fused K=768 loop, 6 chunks of K=128 (128B rows,
//        same XOR-swizzle geometry as the proven bf16 path) -> 12 barriers
//   A  : attn f1z8.f2z8^T K=256 fully staged in ONE barrier-pair (256B rows)
// Scales: zn8/bn8 = 16x normalized (sim acc /256); fz8 = 4x (attn acc /16).
// Numerics: sim abs err ~7.6e-4 -> mask flips ~0.6%, row-averaged loss
// impact ~1e-5..1e-4 vs 5e-4 threshold.
// ---------------------------------------------------------------------------

#define B_N   4096
#define D_N   768
#define HID_N 256
#define NCLS  200

typedef __attribute__((ext_vector_type(8))) short v8s;   // 8 x bf16 (4 VGPRs)
typedef __attribute__((ext_vector_type(4))) float v4f;   // MFMA accumulator

// round-to-nearest-even fp32 -> bf16
__device__ __forceinline__ unsigned short f2bf(float x) {
    unsigned int u = __float_as_uint(x);
    unsigned int r = (u + 0x7FFFu + ((u >> 16) & 1u)) >> 16;
    return (unsigned short)r;
}
__device__ __forceinline__ float bf2f(unsigned short h) {
    return __uint_as_float((unsigned int)h << 16);
}
// fp32 -> OCP e4m3 (RNE, saturating) via HIP type
__device__ __forceinline__ unsigned char f2fp8(float x) {
    __hip_fp8_e4m3 v(x);
    return (unsigned char)v.__x;
}

// async global->LDS, 16 B per lane; lane i lands at ldsbase + i*16
__device__ __forceinline__ void gld16(const unsigned short* g, unsigned short* l) {
    __builtin_amdgcn_global_load_lds(
        (__attribute__((address_space(1))) void*)g,
        (__attribute__((address_space(3))) void*)l, 16, 0, 0);
}
__device__ __forceinline__ void gld16c(const unsigned char* g, unsigned char* l) {
    __builtin_amdgcn_global_load_lds(
        (__attribute__((address_space(1))) void*)g,
        (__attribute__((address_space(3))) void*)l, 16, 0, 0);
}

#define ZERO_ACC(a) { _Pragma("unroll") for (int _i = 0; _i < 4; _i++) \
    _Pragma("unroll") for (int _j = 0; _j < 4; _j++) a[_i][_j] = (v4f){0.f,0.f,0.f,0.f}; }

// ---------------------------------------------------------------------------
// Kernel 1: L2-normalize rows -> fp8 (x16) copies + bf16 raw z for fz_gemm.
// Blocks >= 4096 convert f1_w / f2_w to bf16.
// ---------------------------------------------------------------------------
__global__ __launch_bounds__(256) void normalize_k(
    const float* __restrict__ z, const float* __restrict__ base,
    const float* __restrict__ w1, const float* __restrict__ w2,
    unsigned char* __restrict__ zn8, unsigned char* __restrict__ bn8,
    unsigned short* __restrict__ zb,
    unsigned short* __restrict__ o1, unsigned short* __restrict__ o2)
{
    int tid = threadIdx.x;
    if (blockIdx.x >= B_N) {                     // weight conversion tail
        int b2 = blockIdx.x - B_N;               // 0..7
        const float* src = (b2 < 4) ? w1 : w2;
        unsigned short* dst = (b2 < 4) ? o1 : o2;
        int base2 = (b2 & 3) * 49152 + tid;      // 196608/4 per block
        #pragma unroll 4
        for (int i = 0; i < 192; i++) dst[base2 + i * 256] = f2bf(src[base2 + i * 256]);
        return;
    }
    int row = blockIdx.x;
    __shared__ float ws1[4], ws2[4];
    const float* zr = z    + (size_t)row * D_N;
    const float* br = base + (size_t)row * D_N;
    float z0 = zr[tid], z1 = zr[tid + 256], z2 = zr[tid + 512];
    float b0 = br[tid], b1 = br[tid + 256], b2 = br[tid + 512];
    float s1 = z0*z0 + z1*z1 + z2*z2;
    float s2 = b0*b0 + b1*b1 + b2*b2;
    #pragma unroll
    for (int m = 32; m > 0; m >>= 1) { s1 += __shfl_xor(s1, m); s2 += __shfl_xor(s2, m); }
    if ((tid & 63) == 0) { ws1[tid >> 6] = s1; ws2[tid >> 6] = s2; }
    __syncthreads();
    float t1 = ws1[0] + ws1[1] + ws1[2] + ws1[3];
    float t2 = ws2[0] + ws2[1] + ws2[2] + ws2[3];
    float sc1 = 16.0f / fmaxf(sqrtf(t1), 1e-12f);   // x16 scale into fp8
    float sc2 = 16.0f / fmaxf(sqrtf(t2), 1e-12f);
    size_t o = (size_t)row * D_N;
    zn8[o+tid] = f2fp8(z0*sc1); zn8[o+tid+256] = f2fp8(z1*sc1); zn8[o+tid+512] = f2fp8(z2*sc1);
    bn8[o+tid] = f2fp8(b0*sc2); bn8[o+tid+256] = f2fp8(b1*sc2); bn8[o+tid+512] = f2fp8(b2*sc2);
    zb[o+tid] = f2bf(z0);       zb[o+tid+256] = f2bf(z1);       zb[o+tid+512] = f2bf(z2);
}

// ---------------------------------------------------------------------------
// Shared mini-GEMM (bf16, proven): block tile 128x128, 2x2 wave grid,
// XOR-swizzled unpadded LDS (stride 64 ushorts). Used by fz_gemm only.
// ---------------------------------------------------------------------------
__device__ __forceinline__ void mm_tile128(
    const unsigned short* __restrict__ Ag, const unsigned short* __restrict__ Bg,
    int aRow0, int bRow0, int K,
    unsigned short* Al, unsigned short* Bl, v4f acc[4][4])
{
    const int tid = threadIdx.x;
    const int lane = tid & 63, wave = tid >> 6, quad = lane >> 4, col = lane & 15;
    const int wr = wave >> 1, wc = wave & 1;
    const int r8 = lane >> 3;
    const int kbl = (lane & 7) ^ r8;
    const int sw  = col & 7;
    for (int kc = 0; kc < K; kc += 64) {
        __syncthreads();
        #pragma unroll
        for (int s = 0; s < 4; s++) {
            int rowbase = s * 32 + wave * 8;
            gld16(Ag + (size_t)(aRow0 + rowbase + r8) * K + kc + kbl * 8,
                  Al + rowbase * 64);
            gld16(Bg + (size_t)(bRow0 + rowbase + r8) * K + kc + kbl * 8,
                  Bl + rowbase * 64);
        }
        __syncthreads();
        #pragma unroll
        for (int kk = 0; kk < 2; kk++) {
            int ko = (((kk << 2) + quad) ^ sw) << 3;
            v8s af[4], bf[4];
            #pragma unroll
            for (int t = 0; t < 4; t++) {
                af[t] = *(const v8s*)(Al + (wr * 64 + t * 16 + col) * 64 + ko);
                bf[t] = *(const v8s*)(Bl + (wc * 64 + t * 16 + col) * 64 + ko);
            }
            #pragma unroll
            for (int tr = 0; tr < 4; tr++)
                #pragma unroll
                for (int tc = 0; tc < 4; tc++)
                    acc[tr][tc] = __builtin_amdgcn_mfma_f32_16x16x32_bf16(
                        af[tr], bf[tc], acc[tr][tc], 0, 0, 0);
        }
    }
}

// ---------------------------------------------------------------------------
// Kernel 2: fz = z @ W^T + b for BOTH weights; outputs fp8 (x4). grid (32,4).
// ---------------------------------------------------------------------------
__global__ __launch_bounds__(256, 2) void fz_gemm(
    const unsigned short* __restrict__ zb,
    const unsigned short* __restrict__ w1b, const unsigned short* __restrict__ w2b,
    const float* __restrict__ b1, const float* __restrict__ b2,
    unsigned char* __restrict__ f1z8, unsigned char* __restrict__ f2z8)
{
    __shared__ __align__(16) unsigned short Al[128 * 64];
    __shared__ __align__(16) unsigned short Bl[128 * 64];
    int which = blockIdx.y >> 1;
    const unsigned short* wb = which ? w2b : w1b;
    const float* bias = which ? b2 : b1;
    unsigned char* outz = which ? f2z8 : f1z8;
    int mBase = blockIdx.x * 128, nBase = (blockIdx.y & 1) * 128;
    v4f acc[4][4]; ZERO_ACC(acc);
    mm_tile128(zb, wb, mBase, nBase, D_N, Al, Bl, acc);
    int tid = threadIdx.x, lane = tid & 63, wave = tid >> 6, quad = lane >> 4, col = lane & 15;
    int wr = wave >> 1, wc = wave & 1;
    #pragma unroll
    for (int tr = 0; tr < 4; tr++)
        #pragma unroll
        for (int tc = 0; tc < 4; tc++) {
            int gcol = nBase + wc * 64 + tc * 16 + col;
            float bv = bias[gcol];
            #pragma unroll
            for (int reg = 0; reg < 4; reg++) {
                int grow = mBase + wr * 64 + tr * 16 + quad * 4 + reg;
                outz[(size_t)grow * HID_N + gcol] = f2fp8(4.0f * (acc[tr][tc][reg] + bv));
            }
        }
}

// ---------------------------------------------------------------------------
// Kernel 3: per-row softmax over gathered logits; atomic-free partials.
// ---------------------------------------------------------------------------
__global__ __launch_bounds__(256) void softmax_mean(
    const float* __restrict__ logits, const int* __restrict__ oldi,
    const int* __restrict__ newi, float* __restrict__ mpart)
{
    __shared__ int act[256];
    __shared__ float accs[4][256];
    int tid = threadIdx.x, lane = tid & 63, wave = tid >> 6;
    if (tid < NCLS) act[tid] = (tid < 100) ? oldi[tid] : newi[tid - 100];
    accs[0][tid] = 0.f; accs[1][tid] = 0.f; accs[2][tid] = 0.f; accs[3][tid] = 0.f;
    __syncthreads();
    int a0 = act[lane], a1 = act[lane + 64], a2 = act[lane + 128];
    int a3 = (lane < 8) ? act[lane + 192] : 0;
    int r0 = blockIdx.x * 16 + wave * 4;
    float c0 = 0.f, c1 = 0.f, c2 = 0.f, c3 = 0.f;
    for (int i = 0; i < 4; i++) {
        const float* lr = logits + (size_t)(r0 + i) * NCLS;
        float x0 = lr[a0], x1 = lr[a1], x2 = lr[a2];
        float x3 = (lane < 8) ? lr[a3] : -3.0e38f;
        float m = fmaxf(fmaxf(x0, x1), fmaxf(x2, x3));
        #pragma unroll
        for (int s = 32; s > 0; s >>= 1) m = fmaxf(m, __shfl_xor(m, s));
        float e0 = __expf(x0 - m), e1 = __expf(x1 - m), e2 = __expf(x2 - m);
        float e3 = (lane < 8) ? __expf(x3 - m) : 0.f;
        float sm = e0 + e1 + e2 + e3;
        #pragma unroll
        for (int s = 32; s > 0; s >>= 1) sm += __shfl_xor(sm, s);
        float inv = 1.0f / sm;
        c0 += e0 * inv; c1 += e1 * inv; c2 += e2 * inv; c3 += e3 * inv;
    }
    accs[wave][lane] = c0; accs[wave][lane + 64] = c1; accs[wave][lane + 128] = c2;
    if (lane < 8) accs[wave][lane + 192] = c3;
    __syncthreads();
    mpart[(size_t)tid * 256 + blockIdx.x] =
        accs[0][tid] + accs[1][tid] + accs[2][tid] + accs[3][tid];
}

// ---------------------------------------------------------------------------
// Kernel 4: fused contrastive main, fp8. grid (32, 32); 128x128 tile.
// MS phase: 6 chunks of K=128 (128B rows, granule-XOR swizzle, 2-way-free
// banks); attn: K=256 fully staged in one barrier-pair (256B rows).
// ---------------------------------------------------------------------------
__global__ __launch_bounds__(256, 2) void main_fused(
    const unsigned char* __restrict__ zn8, const unsigned char* __restrict__ bn8,
    const unsigned char* __restrict__ f1z8, const unsigned char* __restrict__ f2z8,
    float* __restrict__ partials)
{
    __shared__ __align__(16) unsigned char S[4 * 128 * 128];   // 64 KB
    unsigned char* S0 = S;
    unsigned char* S1 = S + 1 * 128 * 128;
    unsigned char* S2 = S + 2 * 128 * 128;
    unsigned char* S3 = S + 3 * 128 * 128;
    int tid = threadIdx.x, lane = tid & 63, wave = tid >> 6, quad = lane >> 4, col = lane & 15;
    int wr = wave >> 1, wc = wave & 1;
    int ib = blockIdx.x, jc = blockIdx.y;
    int rBase = ib * 128 + wr * 64;
    int cBase = jc * 128 + wc * 64;
    const int r8 = lane >> 3;
    const int kbl8 = (lane & 7) ^ r8;    // MS staging granule (16B) swizzle

    // ===== MS: mask (bn8) + sim (zn8), K=768 in 6 chunks of 128 =====
    v4f accB[4][4], accS[4][4];
    ZERO_ACC(accB); ZERO_ACC(accS);
    for (int kc = 0; kc < D_N; kc += 128) {
        __syncthreads();
        #pragma unroll
        for (int s = 0; s < 4; s++) {
            int rowbase = s * 32 + wave * 8;
            size_t rOff = (size_t)(ib * 128 + rowbase + r8) * D_N + kc + kbl8 * 16;
            size_t cOff = (size_t)(jc * 128 + rowbase + r8) * D_N + kc + kbl8 * 16;
            gld16c(bn8 + rOff, S0 + rowbase * 128);
            gld16c(bn8 + cOff, S1 + rowbase * 128);
            gld16c(zn8 + rOff, S2 + rowbase * 128);
            gld16c(zn8 + cOff, S3 + rowbase * 128);
        }
        __syncthreads();
        #pragma unroll
        for (int kk = 0; kk < 4; kk++) {
            int gbase = kk * 2 + (quad >> 1);
            int off = ((gbase ^ (col & 7)) * 16) + (quad & 1) * 8;
            long a1[4], b1[4], a2[4], b2[4];
            #pragma unroll
            for (int t = 0; t < 4; t++) {
                int rA = (wr * 64 + t * 16 + col) * 128;
                int rB = (wc * 64 + t * 16 + col) * 128;
                a1[t] = *(const long*)(S0 + rA + off);
                b1[t] = *(const long*)(S1 + rB + off);
                a2[t] = *(const long*)(S2 + rA + off);
                b2[t] = *(const long*)(S3 + rB + off);
            }
            #pragma unroll
            for (int tr = 0; tr < 4; tr++)
                #pragma unroll
                for (int tc = 0; tc < 4; tc++) {
                    accB[tr][tc] = __builtin_amdgcn_mfma_f32_16x16x32_fp8_fp8(
                        a1[tr], b1[tc], accB[tr][tc], 0, 0, 0);
                    accS[tr][tc] = __builtin_amdgcn_mfma_f32_16x16x32_fp8_fp8(
                        a2[tr], b2[tc], accS[tr][tc], 0, 0, 0);
                }
        }
    }

    // mask bits from accB (scale 16x16=256: threshold 0.05*256 = 12.8)
    unsigned long long mb = 0ull;
    #pragma unroll
    for (int tr = 0; tr < 4; tr++)
        #pragma unroll
        for (int tc = 0; tc < 4; tc++)
            #pragma unroll
            for (int reg = 0; reg < 4; reg++) {
                int grow = rBase + tr * 16 + quad * 4 + reg;
                int gcol = cBase + tc * 16 + col;
                if (accB[tr][tc][reg] > 12.8f && grow != gcol)
                    mb |= 1ull << (tr * 16 + tc * 4 + reg);
            }

    // dsum + packed bf16 sim values from accS (descale 1/256)
    float dsum[16];
    #pragma unroll
    for (int i = 0; i < 16; i++) dsum[i] = 0.f;
    unsigned int svp[4][4][2];
    #pragma unroll
    for (int tr = 0; tr < 4; tr++)
        #pragma unroll
        for (int tc = 0; tc < 4; tc++) {
            float s0 = accS[tr][tc][0] * 0.00390625f;
            float s1 = accS[tr][tc][1] * 0.00390625f;
            float s2 = accS[tr][tc][2] * 0.00390625f;
            float s3 = accS[tr][tc][3] * 0.00390625f;
            float svv[4] = {s0, s1, s2, s3};
            #pragma unroll
            for (int reg = 0; reg < 4; reg++) {
                int grow = rBase + tr * 16 + quad * 4 + reg;
                int gcol = cBase + tc * 16 + col;
                if (grow != gcol) dsum[tr * 4 + reg] += __expf(svv[reg] * 10.0f);
            }
            svp[tr][tc][0] = ((unsigned int)f2bf(s1) << 16) | f2bf(s0);
            svp[tr][tc][1] = ((unsigned int)f2bf(s3) << 16) | f2bf(s2);
        }

    // ===== attn: f1z8[ib] . f2z8[jc]^T, K=256 fully staged (one pair) =====
    unsigned char* F1 = S0;               // 128 rows x 256 B
    unsigned char* F2 = S0 + 32768;
    v4f accA[4][4]; ZERO_ACC(accA);
    __syncthreads();
    {
        int r4 = lane >> 4;
        #pragma unroll
        for (int s = 0; s < 8; s++) {
            int rowbase = s * 16 + wave * 4;
            int row = rowbase + r4;
            int kb = (lane & 15) ^ (row & 15);
            gld16c(f1z8 + (size_t)(ib * 128 + row) * HID_N + kb * 16, F1 + rowbase * 256);
            gld16c(f2z8 + (size_t)(jc * 128 + row) * HID_N + kb * 16, F2 + rowbase * 256);
        }
    }
    __syncthreads();
    #pragma unroll
    for (int kk = 0; kk < 8; kk++) {
        int gbase = kk * 2 + (quad >> 1);
        int off = ((gbase ^ col) * 16) + (quad & 1) * 8;
        long af[4], bf[4];
        #pragma unroll
        for (int t = 0; t < 4; t++) {
            af[t] = *(const long*)(F1 + (wr * 64 + t * 16 + col) * 256 + off);
            bf[t] = *(const long*)(F2 + (wc * 64 + t * 16 + col) * 256 + off);
        }
        #pragma unroll
        for (int tr = 0; tr < 4; tr++)
            #pragma unroll
            for (int tc = 0; tc < 4; tc++)
                accA[tr][tc] = __builtin_amdgcn_mfma_f32_16x16x32_fp8_fp8(
                    af[tr], bf[tc], accA[tr][tc], 0, 0, 0);
    }

    // ===== combine (attn scale 4x4=16: exp(acc/16)) =====
    float lsum[16], asum[16], nnf[16];
    #pragma unroll
    for (int i = 0; i < 16; i++) { lsum[i] = 0.f; asum[i] = 0.f; nnf[i] = 0.f; }
    #pragma unroll
    for (int tr = 0; tr < 4; tr++)
        #pragma unroll
        for (int tc = 0; tc < 4; tc++)
            #pragma unroll
            for (int reg = 0; reg < 4; reg++) {
                if ((mb >> (tr * 16 + tc * 4 + reg)) & 1ull) {
                    int slot = tr * 4 + reg;
                    float e = __expf(accA[tr][tc][reg] * 0.0625f);
                    unsigned int pk = svp[tr][tc][reg >> 1];
                    float sv = bf2f((unsigned short)((reg & 1) ? (pk >> 16) : (pk & 0xFFFF)));
                    lsum[slot] += e;
                    asum[slot] += e * sv;
                    nnf[slot] += 1.f;
                }
            }

    #pragma unroll
    for (int i = 0; i < 16; i++) {
        #pragma unroll
        for (int m = 1; m < 16; m <<= 1) {
            lsum[i] += __shfl_xor(lsum[i], m);
            asum[i] += __shfl_xor(asum[i], m);
            dsum[i] += __shfl_xor(dsum[i], m);
            nnf[i]  += __shfl_xor(nnf[i], m);
        }
        if (col == 0) {
            int row = rBase + (i >> 2) * 16 + quad * 4 + (i & 3);
            float4 v; v.x = lsum[i]; v.y = asum[i]; v.z = dsum[i]; v.w = nnf[i];
            *(float4*)(partials + ((size_t)row * 64 + jc * 2 + wc) * 4) = v;
        }
    }
}

// ---------------------------------------------------------------------------
// Kernel 5: reduce per-row partials; last block does entropy + combine.
// ---------------------------------------------------------------------------
__global__ __launch_bounds__(256) void row_reduce_fin(
    const float* __restrict__ partials, const float* __restrict__ mpart,
    float* __restrict__ acc, float* __restrict__ out)
{
    int tid = threadIdx.x;
    int row = blockIdx.x * 64 + (tid >> 2);
    int sub = tid & 3;
    const float4* p = (const float4*)partials + (size_t)row * 64 + sub * 16;
    float L = 0.f, A = 0.f, Dn = 0.f, NN = 0.f;
    #pragma unroll
    for (int c = 0; c < 16; c++) { float4 v = p[c]; L += v.x; A += v.y; Dn += v.z; NN += v.w; }
    #pragma unroll
    for (int m = 1; m < 4; m <<= 1) {
        L += __shfl_xor(L, m); A += __shfl_xor(A, m);
        Dn += __shfl_xor(Dn, m); NN += __shfl_xor(NN, m);
    }
    float per = 0.f, val = 0.f;
    if (sub == 0 && NN > 0.5f) {
        per = (logf(Dn + 1e-8f) - 10.0f * (A / L)) / NN;
        val = 1.0f;
    }
    __shared__ float red[256];
    __shared__ float r2s[256];
    __shared__ int amLast;
    red[tid] = per; r2s[tid] = val; __syncthreads();
    for (int s = 128; s > 0; s >>= 1) {
        if (tid < s) { red[tid] += red[tid + s]; r2s[tid] += r2s[tid + s]; }
        __syncthreads();
    }
    if (tid == 0) {
        atomicAdd(&acc[0], red[0]);
        atomicAdd(&acc[1], r2s[0]);
        __threadfence();
        int old = atomicAdd((int*)&acc[2], 1);
        amLast = (old == (int)gridDim.x - 1);
    }
    __syncthreads();
    if (!amLast) return;

    __shared__ float bcast[2];
    float pcl = 0.0f;
    if (tid < NCLS) {
        const float4* mp = (const float4*)(mpart + (size_t)tid * 256);
        float s = 0.f;
        #pragma unroll
        for (int c = 0; c < 64; c++) { float4 v = mp[c]; s += v.x + v.y + v.z + v.w; }
        pcl = s * (1.0f / 4096.0f);
    }
    red[tid] = (tid < 100) ? pcl : 0.0f; __syncthreads();
    for (int s = 128; s > 0; s >>= 1) { if (tid < s) red[tid] += red[tid + s]; __syncthreads(); }
    if (tid == 0) bcast[0] = red[0];
    __syncthreads();
    red[tid] = (tid >= 100 && tid < NCLS) ? pcl : 0.0f; __syncthreads();
    for (int s = 128; s > 0; s >>= 1) { if (tid < s) red[tid] += red[tid + s]; __syncthreads(); }
    if (tid == 0) bcast[1] = red[0];
    __syncthreads();
    float p_old = bcast[0], p_new = bcast[1];

    float t = 0.0f;
    if (tid < 100)       { float q = pcl / (p_old + 1e-8f); t = q * logf(q + 1e-8f); }
    else if (tid < NCLS) { float q = pcl / (p_new + 1e-8f); t = q * logf(q + 1e-8f); }
    red[tid] = t; __syncthreads();
    for (int s = 128; s > 0; s >>= 1) { if (tid < s) red[tid] += red[tid + s]; __syncthreads(); }

    if (tid == 0) {
        float s0 = __hip_atomic_load(&acc[0], __ATOMIC_RELAXED, __HIP_MEMORY_SCOPE_AGENT);
        float s1 = __hip_atomic_load(&acc[1], __ATOMIC_RELAXED, __HIP_MEMORY_SCOPE_AGENT);
        float loss_inter = p_old * logf(p_old + 1e-8f) + p_new * logf(p_new + 1e-8f)
                           + 0.69314718056f;
        float loss_entropy = loss_inter + red[0] + 2.0f * 4.60517018599f;
        float lc = (s1 > 0.5f) ? s0 / s1 : 0.0f;
        out[0] = loss_entropy + lc;
    }
}

// ---------------------------------------------------------------------------
extern "C" void kernel_launch(void* const* d_in, const int* in_sizes, int n_in,
                              void* d_out, int out_size, void* d_ws, size_t ws_size,
                              hipStream_t stream)
{
    const float* z_u    = (const float*)d_in[0];
    const float* logits = (const float*)d_in[1];
    const int*   oldi   = (const int*)d_in[2];
    const int*   newi   = (const int*)d_in[3];
    const float* basef  = (const float*)d_in[4];
    const float* f1w    = (const float*)d_in[5];
    const float* f1b    = (const float*)d_in[6];
    const float* f2w    = (const float*)d_in[7];
    const float* f2b    = (const float*)d_in[8];
    float* out = (float*)d_out;

    unsigned char* zn8   = (unsigned char*)d_ws;           // [B][D] fp8
    unsigned char* bn8   = zn8 + (size_t)B_N * D_N;
    unsigned short* zb   = (unsigned short*)(bn8 + (size_t)B_N * D_N);  // [B][D] bf16
    unsigned short* w1b  = zb  + (size_t)B_N * D_N;        // [HID][D] bf16
    unsigned short* w2b  = w1b + (size_t)HID_N * D_N;
    unsigned char* f1z8  = (unsigned char*)(w2b + (size_t)HID_N * D_N); // [B][HID] fp8
    unsigned char* f2z8  = f1z8 + (size_t)B_N * HID_N;
    float* partials = (float*)(f2z8 + (size_t)B_N * HID_N); // [B][64][4]
    float* mpart    = partials + (size_t)B_N * 64 * 4;      // [256 class][256 blk]
    float* accums   = mpart + 256 * 256;                    // [2] + counter

    hipMemsetAsync(accums, 0, 4 * sizeof(float), stream);

    normalize_k<<<B_N + 8, 256, 0, stream>>>(z_u, basef, f1w, f2w, zn8, bn8, zb, w1b, w2b);
    fz_gemm<<<dim3(B_N / 128, 4), 256, 0, stream>>>(zb, w1b, w2b, f1b, f2b, f1z8, f2z8);
    softmax_mean<<<256, 256, 0, stream>>>(logits, oldi, newi, mpart);
    main_fused<<<dim3(32, 32), 256, 0, stream>>>(zn8, bn8, f1z8, f2z8, partials);
    row_reduce_fin<<<64, 256, 0, stream>>>(partials, mpart, accums, out);
}

// Round 11
// 188.176 us; speedup vs baseline: 1.4686x; 1.0434x over previous
//
#include <hip/hip_runtime.h>
#include <hip/hip_fp8.h>

// ---------------------------------------------------------------------------
// Debiased Representation Loss — fused MI355X implementation (R11).
// R10 fp8 structure (main 68.6us, FETCH halved, absmax 0) + bank-conflict
// fix: fp8 arrays are stored with the two 8-byte halves of each 16-byte
// granule SWAPPED for rows with bit3 set ("half-swap"). Readers XOR the 8B
// sub-slot with col>>3, so each 16-lane quad-group covers all 32 LDS banks
// (was 2-way aliased -> 7.3e6 conflict cycles in R10). Also: attn staging
// DMAs issued before the MS epilogue VALU to hide DMA latency.
// ---------------------------------------------------------------------------

#define B_N   4096
#define D_N   768
#define HID_N 256
#define NCLS  200

typedef __attribute__((ext_vector_type(8))) short v8s;   // 8 x bf16 (4 VGPRs)
typedef __attribute__((ext_vector_type(4))) float v4f;   // MFMA accumulator

// round-to-nearest-even fp32 -> bf16
__device__ __forceinline__ unsigned short f2bf(float x) {
    unsigned int u = __float_as_uint(x);
    unsigned int r = (u + 0x7FFFu + ((u >> 16) & 1u)) >> 16;
    return (unsigned short)r;
}
__device__ __forceinline__ float bf2f(unsigned short h) {
    return __uint_as_float((unsigned int)h << 16);
}
// fp32 -> OCP e4m3 (RNE, saturating) via HIP type
__device__ __forceinline__ unsigned char f2fp8(float x) {
    __hip_fp8_e4m3 v(x);
    return (unsigned char)v.__x;
}

// async global->LDS, 16 B per lane; lane i lands at ldsbase + i*16
__device__ __forceinline__ void gld16(const unsigned short* g, unsigned short* l) {
    __builtin_amdgcn_global_load_lds(
        (__attribute__((address_space(1))) void*)g,
        (__attribute__((address_space(3))) void*)l, 16, 0, 0);
}
__device__ __forceinline__ void gld16c(const unsigned char* g, unsigned char* l) {
    __builtin_amdgcn_global_load_lds(
        (__attribute__((address_space(1))) void*)g,
        (__attribute__((address_space(3))) void*)l, 16, 0, 0);
}

#define ZERO_ACC(a) { _Pragma("unroll") for (int _i = 0; _i < 4; _i++) \
    _Pragma("unroll") for (int _j = 0; _j < 4; _j++) a[_i][_j] = (v4f){0.f,0.f,0.f,0.f}; }

// ---------------------------------------------------------------------------
// Kernel 1: L2-normalize rows -> fp8 (x16, half-swapped) + bf16 raw z.
// Blocks >= 4096 convert f1_w / f2_w to bf16.
// ---------------------------------------------------------------------------
__global__ __launch_bounds__(256) void normalize_k(
    const float* __restrict__ z, const float* __restrict__ base,
    const float* __restrict__ w1, const float* __restrict__ w2,
    unsigned char* __restrict__ zn8, unsigned char* __restrict__ bn8,
    unsigned short* __restrict__ zb,
    unsigned short* __restrict__ o1, unsigned short* __restrict__ o2)
{
    int tid = threadIdx.x;
    if (blockIdx.x >= B_N) {                     // weight conversion tail
        int b2 = blockIdx.x - B_N;               // 0..7
        const float* src = (b2 < 4) ? w1 : w2;
        unsigned short* dst = (b2 < 4) ? o1 : o2;
        int base2 = (b2 & 3) * 49152 + tid;      // 196608/4 per block
        #pragma unroll 4
        for (int i = 0; i < 192; i++) dst[base2 + i * 256] = f2bf(src[base2 + i * 256]);
        return;
    }
    int row = blockIdx.x;
    __shared__ float ws1[4], ws2[4];
    const float* zr = z    + (size_t)row * D_N;
    const float* br = base + (size_t)row * D_N;
    float z0 = zr[tid], z1 = zr[tid + 256], z2 = zr[tid + 512];
    float b0 = br[tid], b1 = br[tid + 256], b2 = br[tid + 512];
    float s1 = z0*z0 + z1*z1 + z2*z2;
    float s2 = b0*b0 + b1*b1 + b2*b2;
    #pragma unroll
    for (int m = 32; m > 0; m >>= 1) { s1 += __shfl_xor(s1, m); s2 += __shfl_xor(s2, m); }
    if ((tid & 63) == 0) { ws1[tid >> 6] = s1; ws2[tid >> 6] = s2; }
    __syncthreads();
    float t1 = ws1[0] + ws1[1] + ws1[2] + ws1[3];
    float t2 = ws2[0] + ws2[1] + ws2[2] + ws2[3];
    float sc1 = 16.0f / fmaxf(sqrtf(t1), 1e-12f);   // x16 scale into fp8
    float sc2 = 16.0f / fmaxf(sqrtf(t2), 1e-12f);
    size_t o = (size_t)row * D_N;
    int sw8 = ((row >> 3) & 1) << 3;                // half-swap key (row bit3)
    int j0 = tid ^ sw8;
    zn8[o+j0] = f2fp8(z0*sc1); zn8[o+j0+256] = f2fp8(z1*sc1); zn8[o+j0+512] = f2fp8(z2*sc1);
    bn8[o+j0] = f2fp8(b0*sc2); bn8[o+j0+256] = f2fp8(b1*sc2); bn8[o+j0+512] = f2fp8(b2*sc2);
    zb[o+tid] = f2bf(z0);      zb[o+tid+256] = f2bf(z1);      zb[o+tid+512] = f2bf(z2);
}

// ---------------------------------------------------------------------------
// Shared mini-GEMM (bf16, proven): used by fz_gemm only.
// ---------------------------------------------------------------------------
__device__ __forceinline__ void mm_tile128(
    const unsigned short* __restrict__ Ag, const unsigned short* __restrict__ Bg,
    int aRow0, int bRow0, int K,
    unsigned short* Al, unsigned short* Bl, v4f acc[4][4])
{
    const int tid = threadIdx.x;
    const int lane = tid & 63, wave = tid >> 6, quad = lane >> 4, col = lane & 15;
    const int wr = wave >> 1, wc = wave & 1;
    const int r8 = lane >> 3;
    const int kbl = (lane & 7) ^ r8;
    const int sw  = col & 7;
    for (int kc = 0; kc < K; kc += 64) {
        __syncthreads();
        #pragma unroll
        for (int s = 0; s < 4; s++) {
            int rowbase = s * 32 + wave * 8;
            gld16(Ag + (size_t)(aRow0 + rowbase + r8) * K + kc + kbl * 8,
                  Al + rowbase * 64);
            gld16(Bg + (size_t)(bRow0 + rowbase + r8) * K + kc + kbl * 8,
                  Bl + rowbase * 64);
        }
        __syncthreads();
        #pragma unroll
        for (int kk = 0; kk < 2; kk++) {
            int ko = (((kk << 2) + quad) ^ sw) << 3;
            v8s af[4], bf[4];
            #pragma unroll
            for (int t = 0; t < 4; t++) {
                af[t] = *(const v8s*)(Al + (wr * 64 + t * 16 + col) * 64 + ko);
                bf[t] = *(const v8s*)(Bl + (wc * 64 + t * 16 + col) * 64 + ko);
            }
            #pragma unroll
            for (int tr = 0; tr < 4; tr++)
                #pragma unroll
                for (int tc = 0; tc < 4; tc++)
                    acc[tr][tc] = __builtin_amdgcn_mfma_f32_16x16x32_bf16(
                        af[tr], bf[tc], acc[tr][tc], 0, 0, 0);
        }
    }
}

// ---------------------------------------------------------------------------
// Kernel 2: fz = z @ W^T + b; outputs fp8 (x4, half-swapped). grid (32,4).
// ---------------------------------------------------------------------------
__global__ __launch_bounds__(256, 2) void fz_gemm(
    const unsigned short* __restrict__ zb,
    const unsigned short* __restrict__ w1b, const unsigned short* __restrict__ w2b,
    const float* __restrict__ b1, const float* __restrict__ b2,
    unsigned char* __restrict__ f1z8, unsigned char* __restrict__ f2z8)
{
    __shared__ __align__(16) unsigned short Al[128 * 64];
    __shared__ __align__(16) unsigned short Bl[128 * 64];
    int which = blockIdx.y >> 1;
    const unsigned short* wb = which ? w2b : w1b;
    const float* bias = which ? b2 : b1;
    unsigned char* outz = which ? f2z8 : f1z8;
    int mBase = blockIdx.x * 128, nBase = (blockIdx.y & 1) * 128;
    v4f acc[4][4]; ZERO_ACC(acc);
    mm_tile128(zb, wb, mBase, nBase, D_N, Al, Bl, acc);
    int tid = threadIdx.x, lane = tid & 63, wave = tid >> 6, quad = lane >> 4, col = lane & 15;
    int wr = wave >> 1, wc = wave & 1;
    #pragma unroll
    for (int tr = 0; tr < 4; tr++)
        #pragma unroll
        for (int tc = 0; tc < 4; tc++) {
            int gcol = nBase + wc * 64 + tc * 16 + col;
            float bv = bias[gcol];
            #pragma unroll
            for (int reg = 0; reg < 4; reg++) {
                int grow = mBase + wr * 64 + tr * 16 + quad * 4 + reg;
                int sw8 = ((grow >> 3) & 1) << 3;      // half-swap key
                outz[(size_t)grow * HID_N + (gcol ^ sw8)] =
                    f2fp8(4.0f * (acc[tr][tc][reg] + bv));
            }
        }
}

// ---------------------------------------------------------------------------
// Kernel 3: per-row softmax over gathered logits; atomic-free partials.
// ---------------------------------------------------------------------------
__global__ __launch_bounds__(256) void softmax_mean(
    const float* __restrict__ logits, const int* __restrict__ oldi,
    const int* __restrict__ newi, float* __restrict__ mpart)
{
    __shared__ int act[256];
    __shared__ float accs[4][256];
    int tid = threadIdx.x, lane = tid & 63, wave = tid >> 6;
    if (tid < NCLS) act[tid] = (tid < 100) ? oldi[tid] : newi[tid - 100];
    accs[0][tid] = 0.f; accs[1][tid] = 0.f; accs[2][tid] = 0.f; accs[3][tid] = 0.f;
    __syncthreads();
    int a0 = act[lane], a1 = act[lane + 64], a2 = act[lane + 128];
    int a3 = (lane < 8) ? act[lane + 192] : 0;
    int r0 = blockIdx.x * 16 + wave * 4;
    float c0 = 0.f, c1 = 0.f, c2 = 0.f, c3 = 0.f;
    for (int i = 0; i < 4; i++) {
        const float* lr = logits + (size_t)(r0 + i) * NCLS;
        float x0 = lr[a0], x1 = lr[a1], x2 = lr[a2];
        float x3 = (lane < 8) ? lr[a3] : -3.0e38f;
        float m = fmaxf(fmaxf(x0, x1), fmaxf(x2, x3));
        #pragma unroll
        for (int s = 32; s > 0; s >>= 1) m = fmaxf(m, __shfl_xor(m, s));
        float e0 = __expf(x0 - m), e1 = __expf(x1 - m), e2 = __expf(x2 - m);
        float e3 = (lane < 8) ? __expf(x3 - m) : 0.f;
        float sm = e0 + e1 + e2 + e3;
        #pragma unroll
        for (int s = 32; s > 0; s >>= 1) sm += __shfl_xor(sm, s);
        float inv = 1.0f / sm;
        c0 += e0 * inv; c1 += e1 * inv; c2 += e2 * inv; c3 += e3 * inv;
    }
    accs[wave][lane] = c0; accs[wave][lane + 64] = c1; accs[wave][lane + 128] = c2;
    if (lane < 8) accs[wave][lane + 192] = c3;
    __syncthreads();
    mpart[(size_t)tid * 256 + blockIdx.x] =
        accs[0][tid] + accs[1][tid] + accs[2][tid] + accs[3][tid];
}

// ---------------------------------------------------------------------------
// Kernel 4: fused contrastive main, fp8. grid (32, 32); 128x128 tile.
// MS: 6 chunks of K=128 (128B rows); attn: K=256 in one barrier-pair.
// Conflict-free b64 reads via half-swap + (quad&1)^(col>>3) sub-slot.
// ---------------------------------------------------------------------------
__global__ __launch_bounds__(256, 2) void main_fused(
    const unsigned char* __restrict__ zn8, const unsigned char* __restrict__ bn8,
    const unsigned char* __restrict__ f1z8, const unsigned char* __restrict__ f2z8,
    float* __restrict__ partials)
{
    __shared__ __align__(16) unsigned char S[4 * 128 * 128];   // 64 KB
    unsigned char* S0 = S;
    unsigned char* S1 = S + 1 * 128 * 128;
    unsigned char* S2 = S + 2 * 128 * 128;
    unsigned char* S3 = S + 3 * 128 * 128;
    int tid = threadIdx.x, lane = tid & 63, wave = tid >> 6, quad = lane >> 4, col = lane & 15;
    int wr = wave >> 1, wc = wave & 1;
    int ib = blockIdx.x, jc = blockIdx.y;
    int rBase = ib * 128 + wr * 64;
    int cBase = jc * 128 + wc * 64;
    const int r8 = lane >> 3;
    const int kbl8 = (lane & 7) ^ r8;    // MS staging granule (16B) swizzle
    const int sub8 = ((quad & 1) ^ (col >> 3)) << 3;   // conflict-free sub-slot

    // ===== MS: mask (bn8) + sim (zn8), K=768 in 6 chunks of 128 =====
    v4f accB[4][4], accS[4][4];
    ZERO_ACC(accB); ZERO_ACC(accS);
    for (int kc = 0; kc < D_N; kc += 128) {
        __syncthreads();
        #pragma unroll
        for (int s = 0; s < 4; s++) {
            int rowbase = s * 32 + wave * 8;
            size_t rOff = (size_t)(ib * 128 + rowbase + r8) * D_N + kc + kbl8 * 16;
            size_t cOff = (size_t)(jc * 128 + rowbase + r8) * D_N + kc + kbl8 * 16;
            gld16c(bn8 + rOff, S0 + rowbase * 128);
            gld16c(bn8 + cOff, S1 + rowbase * 128);
            gld16c(zn8 + rOff, S2 + rowbase * 128);
            gld16c(zn8 + cOff, S3 + rowbase * 128);
        }
        __syncthreads();
        #pragma unroll
        for (int kk = 0; kk < 4; kk++) {
            int gbase = kk * 2 + (quad >> 1);
            int off = ((gbase ^ (col & 7)) << 4) + sub8;
            long a1[4], b1[4], a2[4], b2[4];
            #pragma unroll
            for (int t = 0; t < 4; t++) {
                int rA = (wr * 64 + t * 16 + col) * 128;
                int rB = (wc * 64 + t * 16 + col) * 128;
                a1[t] = *(const long*)(S0 + rA + off);
                b1[t] = *(const long*)(S1 + rB + off);
                a2[t] = *(const long*)(S2 + rA + off);
                b2[t] = *(const long*)(S3 + rB + off);
            }
            #pragma unroll
            for (int tr = 0; tr < 4; tr++)
                #pragma unroll
                for (int tc = 0; tc < 4; tc++) {
                    accB[tr][tc] = __builtin_amdgcn_mfma_f32_16x16x32_fp8_fp8(
                        a1[tr], b1[tc], accB[tr][tc], 0, 0, 0);
                    accS[tr][tc] = __builtin_amdgcn_mfma_f32_16x16x32_fp8_fp8(
                        a2[tr], b2[tc], accS[tr][tc], 0, 0, 0);
                }
        }
    }

    // ===== issue attn staging DMAs now; epilogue VALU overlaps the DMA =====
    unsigned char* F1 = S0;               // 128 rows x 256 B
    unsigned char* F2 = S0 + 32768;
    __syncthreads();                      // all MS LDS reads complete
    {
        int r4 = lane >> 4;
        #pragma unroll
        for (int s = 0; s < 8; s++) {
            int rowbase = s * 16 + wave * 4;
            int row = rowbase + r4;
            int kb = (lane & 15) ^ (row & 15);
            gld16c(f1z8 + (size_t)(ib * 128 + row) * HID_N + kb * 16, F1 + rowbase * 256);
            gld16c(f2z8 + (size_t)(jc * 128 + row) * HID_N + kb * 16, F2 + rowbase * 256);
        }
    }

    // mask bits from accB (scale 16x16=256: threshold 0.05*256 = 12.8)
    unsigned long long mb = 0ull;
    #pragma unroll
    for (int tr = 0; tr < 4; tr++)
        #pragma unroll
        for (int tc = 0; tc < 4; tc++)
            #pragma unroll
            for (int reg = 0; reg < 4; reg++) {
                int grow = rBase + tr * 16 + quad * 4 + reg;
                int gcol = cBase + tc * 16 + col;
                if (accB[tr][tc][reg] > 12.8f && grow != gcol)
                    mb |= 1ull << (tr * 16 + tc * 4 + reg);
            }

    // dsum + packed bf16 sim values from accS (descale 1/256)
    float dsum[16];
    #pragma unroll
    for (int i = 0; i < 16; i++) dsum[i] = 0.f;
    unsigned int svp[4][4][2];
    #pragma unroll
    for (int tr = 0; tr < 4; tr++)
        #pragma unroll
        for (int tc = 0; tc < 4; tc++) {
            float s0 = accS[tr][tc][0] * 0.00390625f;
            float s1 = accS[tr][tc][1] * 0.00390625f;
            float s2 = accS[tr][tc][2] * 0.00390625f;
            float s3 = accS[tr][tc][3] * 0.00390625f;
            float svv[4] = {s0, s1, s2, s3};
            #pragma unroll
            for (int reg = 0; reg < 4; reg++) {
                int grow = rBase + tr * 16 + quad * 4 + reg;
                int gcol = cBase + tc * 16 + col;
                if (grow != gcol) dsum[tr * 4 + reg] += __expf(svv[reg] * 10.0f);
            }
            svp[tr][tc][0] = ((unsigned int)f2bf(s1) << 16) | f2bf(s0);
            svp[tr][tc][1] = ((unsigned int)f2bf(s3) << 16) | f2bf(s2);
        }

    // ===== attn: f1z8[ib] . f2z8[jc]^T, K=256 fully staged =====
    v4f accA[4][4]; ZERO_ACC(accA);
    __syncthreads();                      // DMA drained
    #pragma unroll
    for (int kk = 0; kk < 8; kk++) {
        int gbase = kk * 2 + (quad >> 1);
        int off = ((gbase ^ col) << 4) + sub8;
        long af[4], bf[4];
        #pragma unroll
        for (int t = 0; t < 4; t++) {
            af[t] = *(const long*)(F1 + (wr * 64 + t * 16 + col) * 256 + off);
            bf[t] = *(const long*)(F2 + (wc * 64 + t * 16 + col) * 256 + off);
        }
        #pragma unroll
        for (int tr = 0; tr < 4; tr++)
            #pragma unroll
            for (int tc = 0; tc < 4; tc++)
                accA[tr][tc] = __builtin_amdgcn_mfma_f32_16x16x32_fp8_fp8(
                    af[tr], bf[tc], accA[tr][tc], 0, 0, 0);
    }

    // ===== combine (attn scale 4x4=16: exp(acc/16)) =====
    float lsum[16], asum[16], nnf[16];
    #pragma unroll
    for (int i = 0; i < 16; i++) { lsum[i] = 0.f; asum[i] = 0.f; nnf[i] = 0.f; }
    #pragma unroll
    for (int tr = 0; tr < 4; tr++)
        #pragma unroll
        for (int tc = 0; tc < 4; tc++)
            #pragma unroll
            for (int reg = 0; reg < 4; reg++) {
                if ((mb >> (tr * 16 + tc * 4 + reg)) & 1ull) {
                    int slot = tr * 4 + reg;
                    float e = __expf(accA[tr][tc][reg] * 0.0625f);
                    unsigned int pk = svp[tr][tc][reg >> 1];
                    float sv = bf2f((unsigned short)((reg & 1) ? (pk >> 16) : (pk & 0xFFFF)));
                    lsum[slot] += e;
                    asum[slot] += e * sv;
                    nnf[slot] += 1.f;
                }
            }

    #pragma unroll
    for (int i = 0; i < 16; i++) {
        #pragma unroll
        for (int m = 1; m < 16; m <<= 1) {
            lsum[i] += __shfl_xor(lsum[i], m);
            asum[i] += __shfl_xor(asum[i], m);
            dsum[i] += __shfl_xor(dsum[i], m);
            nnf[i]  += __shfl_xor(nnf[i], m);
        }
        if (col == 0) {
            int row = rBase + (i >> 2) * 16 + quad * 4 + (i & 3);
            float4 v; v.x = lsum[i]; v.y = asum[i]; v.z = dsum[i]; v.w = nnf[i];
            *(float4*)(partials + ((size_t)row * 64 + jc * 2 + wc) * 4) = v;
        }
    }
}

// ---------------------------------------------------------------------------
// Kernel 5: reduce per-row partials; last block does entropy + combine.
// ---------------------------------------------------------------------------
__global__ __launch_bounds__(256) void row_reduce_fin(
    const float* __restrict__ partials, const float* __restrict__ mpart,
    float* __restrict__ acc, float* __restrict__ out)
{
    int tid = threadIdx.x;
    int row = blockIdx.x * 64 + (tid >> 2);
    int sub = tid & 3;
    const float4* p = (const float4*)partials + (size_t)row * 64 + sub * 16;
    float L = 0.f, A = 0.f, Dn = 0.f, NN = 0.f;
    #pragma unroll
    for (int c = 0; c < 16; c++) { float4 v = p[c]; L += v.x; A += v.y; Dn += v.z; NN += v.w; }
    #pragma unroll
    for (int m = 1; m < 4; m <<= 1) {
        L += __shfl_xor(L, m); A += __shfl_xor(A, m);
        Dn += __shfl_xor(Dn, m); NN += __shfl_xor(NN, m);
    }
    float per = 0.f, val = 0.f;
    if (sub == 0 && NN > 0.5f) {
        per = (logf(Dn + 1e-8f) - 10.0f * (A / L)) / NN;
        val = 1.0f;
    }
    __shared__ float red[256];
    __shared__ float r2s[256];
    __shared__ int amLast;
    red[tid] = per; r2s[tid] = val; __syncthreads();
    for (int s = 128; s > 0; s >>= 1) {
        if (tid < s) { red[tid] += red[tid + s]; r2s[tid] += r2s[tid + s]; }
        __syncthreads();
    }
    if (tid == 0) {
        atomicAdd(&acc[0], red[0]);
        atomicAdd(&acc[1], r2s[0]);
        __threadfence();
        int old = atomicAdd((int*)&acc[2], 1);
        amLast = (old == (int)gridDim.x - 1);
    }
    __syncthreads();
    if (!amLast) return;

    __shared__ float bcast[2];
    float pcl = 0.0f;
    if (tid < NCLS) {
        const float4* mp = (const float4*)(mpart + (size_t)tid * 256);
        float s = 0.f;
        #pragma unroll
        for (int c = 0; c < 64; c++) { float4 v = mp[c]; s += v.x + v.y + v.z + v.w; }
        pcl = s * (1.0f / 4096.0f);
    }
    red[tid] = (tid < 100) ? pcl : 0.0f; __syncthreads();
    for (int s = 128; s > 0; s >>= 1) { if (tid < s) red[tid] += red[tid + s]; __syncthreads(); }
    if (tid == 0) bcast[0] = red[0];
    __syncthreads();
    red[tid] = (tid >= 100 && tid < NCLS) ? pcl : 0.0f; __syncthreads();
    for (int s = 128; s > 0; s >>= 1) { if (tid < s) red[tid] += red[tid + s]; __syncthreads(); }
    if (tid == 0) bcast[1] = red[0];
    __syncthreads();
    float p_old = bcast[0], p_new = bcast[1];

    float t = 0.0f;
    if (tid < 100)       { float q = pcl / (p_old + 1e-8f); t = q * logf(q + 1e-8f); }
    else if (tid < NCLS) { float q = pcl / (p_new + 1e-8f); t = q * logf(q + 1e-8f); }
    red[tid] = t; __syncthreads();
    for (int s = 128; s > 0; s >>= 1) { if (tid < s) red[tid] += red[tid + s]; __syncthreads(); }

    if (tid == 0) {
        float s0 = __hip_atomic_load(&acc[0], __ATOMIC_RELAXED, __HIP_MEMORY_SCOPE_AGENT);
        float s1 = __hip_atomic_load(&acc[1], __ATOMIC_RELAXED, __HIP_MEMORY_SCOPE_AGENT);
        float loss_inter = p_old * logf(p_old + 1e-8f) + p_new * logf(p_new + 1e-8f)
                           + 0.69314718056f;
        float loss_entropy = loss_inter + red[0] + 2.0f * 4.60517018599f;
        float lc = (s1 > 0.5f) ? s0 / s1 : 0.0f;
        out[0] = loss_entropy + lc;
    }
}

// ---------------------------------------------------------------------------
extern "C" void kernel_launch(void* const* d_in, const int* in_sizes, int n_in,
                              void* d_out, int out_size, void* d_ws, size_t ws_size,
                              hipStream_t stream)
{
    const float* z_u    = (const float*)d_in[0];
    const float* logits = (const float*)d_in[1];
    const int*   oldi   = (const int*)d_in[2];
    const int*   newi   = (const int*)d_in[3];
    const float* basef  = (const float*)d_in[4];
    const float* f1w    = (const float*)d_in[5];
    const float* f1b    = (const float*)d_in[6];
    const float* f2w    = (const float*)d_in[7];
    const float* f2b    = (const float*)d_in[8];
    float* out = (float*)d_out;

    unsigned char* zn8   = (unsigned char*)d_ws;           // [B][D] fp8
    unsigned char* bn8   = zn8 + (size_t)B_N * D_N;
    unsigned short* zb   = (unsigned short*)(bn8 + (size_t)B_N * D_N);  // [B][D] bf16
    unsigned short* w1b  = zb  + (size_t)B_N * D_N;        // [HID][D] bf16
    unsigned short* w2b  = w1b + (size_t)HID_N * D_N;
    unsigned char* f1z8  = (unsigned char*)(w2b + (size_t)HID_N * D_N); // [B][HID] fp8
    unsigned char* f2z8  = f1z8 + (size_t)B_N * HID_N;
    float* partials = (float*)(f2z8 + (size_t)B_N * HID_N); // [B][64][4]
    float* mpart    = partials + (size_t)B_N * 64 * 4;      // [256 class][256 blk]
    float* accums   = mpart + 256 * 256;                    // [2] + counter

    hipMemsetAsync(accums, 0, 4 * sizeof(float), stream);

    normalize_k<<<B_N + 8, 256, 0, stream>>>(z_u, basef, f1w, f2w, zn8, bn8, zb, w1b, w2b);
    fz_gemm<<<dim3(B_N / 128, 4), 256, 0, stream>>>(zb, w1b, w2b, f1b, f2b, f1z8, f2z8);
    softmax_mean<<<256, 256, 0, stream>>>(logits, oldi, newi, mpart);
    main_fused<<<dim3(32, 32), 256, 0, stream>>>(zn8, bn8, f1z8, f2z8, partials);
    row_reduce_fin<<<64, 256, 0, stream>>>(partials, mpart, accums, out);
}

// Round 12
// 177.394 us; speedup vs baseline: 1.5579x; 1.0608x over previous
//
#include <hip/hip_runtime.h>
#include <hip/hip_fp8.h>

// ---------------------------------------------------------------------------
// Debiased Representation Loss — fused MI355X implementation (R12).
// R11 fp8 main kernel (conflict-free half-swap layout) + 3-node graph:
//   1) pre_all: normalize->fp8 | softmax partials (+accums zero) | fz GEMM
//      (512 blocks of 64x64 tiles, f32 inputs converted inline) — all
//      independent block families in ONE launch.
//   2) main_fused: fp8 contrastive (MS fused K=768, attn K=256, one 64-AGPR
//      pair of acc sets, conflict-free b64 LDS via half-swap sub-slot XOR).
//   3) row_reduce_fin.
// ---------------------------------------------------------------------------

#define B_N   4096
#define D_N   768
#define HID_N 256
#define NCLS  200

typedef __attribute__((ext_vector_type(8))) short v8s;   // 8 x bf16 (4 VGPRs)
typedef __attribute__((ext_vector_type(4))) float v4f;   // MFMA accumulator

// round-to-nearest-even fp32 -> bf16
__device__ __forceinline__ unsigned short f2bf(float x) {
    unsigned int u = __float_as_uint(x);
    unsigned int r = (u + 0x7FFFu + ((u >> 16) & 1u)) >> 16;
    return (unsigned short)r;
}
__device__ __forceinline__ float bf2f(unsigned short h) {
    return __uint_as_float((unsigned int)h << 16);
}
// fp32 -> OCP e4m3 (RNE, saturating)
__device__ __forceinline__ unsigned char f2fp8(float x) {
    __hip_fp8_e4m3 v(x);
    return (unsigned char)v.__x;
}

// async global->LDS, 16 B per lane
__device__ __forceinline__ void gld16c(const unsigned char* g, unsigned char* l) {
    __builtin_amdgcn_global_load_lds(
        (__attribute__((address_space(1))) void*)g,
        (__attribute__((address_space(3))) void*)l, 16, 0, 0);
}

#define ZERO_ACC(a) { _Pragma("unroll") for (int _i = 0; _i < 4; _i++) \
    _Pragma("unroll") for (int _j = 0; _j < 4; _j++) a[_i][_j] = (v4f){0.f,0.f,0.f,0.f}; }

// ---------------------------------------------------------------------------
// Kernel 1: pre_all — three independent block families.
//  [0,4096)    : L2-normalize row -> zn8/bn8 fp8 (x16, half-swapped)
//  [4096,4352) : softmax partials (block 4096 zeroes accums)
//  [4352,4864) : fz = z@W^T+b, 64x64 tiles, f32 in (inline bf16), fp8 out (x4)
// ---------------------------------------------------------------------------
__global__ __launch_bounds__(256) void pre_all(
    const float* __restrict__ z, const float* __restrict__ base,
    const float* __restrict__ w1, const float* __restrict__ w2,
    const float* __restrict__ b1, const float* __restrict__ b2,
    const float* __restrict__ logits, const int* __restrict__ oldi,
    const int* __restrict__ newi,
    unsigned char* __restrict__ zn8, unsigned char* __restrict__ bn8,
    unsigned char* __restrict__ f1z8, unsigned char* __restrict__ f2z8,
    float* __restrict__ mpart, float* __restrict__ accums)
{
    __shared__ __align__(16) unsigned char shmem[2 * 64 * 72 * 2];  // 18.4 KB
    int tid = threadIdx.x;

    if (blockIdx.x < B_N) {
        // ---- normalize ----
        float* ws1 = (float*)shmem;
        float* ws2 = ws1 + 4;
        int row = blockIdx.x;
        const float* zr = z    + (size_t)row * D_N;
        const float* br = base + (size_t)row * D_N;
        float z0 = zr[tid], z1 = zr[tid + 256], z2 = zr[tid + 512];
        float b0 = br[tid], b1v = br[tid + 256], b2v = br[tid + 512];
        float s1 = z0*z0 + z1*z1 + z2*z2;
        float s2 = b0*b0 + b1v*b1v + b2v*b2v;
        #pragma unroll
        for (int m = 32; m > 0; m >>= 1) { s1 += __shfl_xor(s1, m); s2 += __shfl_xor(s2, m); }
        if ((tid & 63) == 0) { ws1[tid >> 6] = s1; ws2[tid >> 6] = s2; }
        __syncthreads();
        float t1 = ws1[0] + ws1[1] + ws1[2] + ws1[3];
        float t2 = ws2[0] + ws2[1] + ws2[2] + ws2[3];
        float sc1 = 16.0f / fmaxf(sqrtf(t1), 1e-12f);
        float sc2 = 16.0f / fmaxf(sqrtf(t2), 1e-12f);
        size_t o = (size_t)row * D_N;
        int j0 = tid ^ (((row >> 3) & 1) << 3);        // half-swap key
        zn8[o+j0] = f2fp8(z0*sc1);  zn8[o+j0+256] = f2fp8(z1*sc1);  zn8[o+j0+512] = f2fp8(z2*sc1);
        bn8[o+j0] = f2fp8(b0*sc2);  bn8[o+j0+256] = f2fp8(b1v*sc2); bn8[o+j0+512] = f2fp8(b2v*sc2);
        return;
    }
    if (blockIdx.x < B_N + 256) {
        // ---- softmax partials: 256 blocks x 16 rows ----
        int* act = (int*)shmem;
        float* accs = (float*)(shmem + 1024);          // [4][256]
        int sb = blockIdx.x - B_N;
        int lane = tid & 63, wave = tid >> 6;
        if (sb == 0 && tid < 4) accums[tid] = 0.0f;
        if (tid < NCLS) act[tid] = (tid < 100) ? oldi[tid] : newi[tid - 100];
        accs[tid] = 0.f; accs[256 + tid] = 0.f; accs[512 + tid] = 0.f; accs[768 + tid] = 0.f;
        __syncthreads();
        int a0 = act[lane], a1 = act[lane + 64], a2 = act[lane + 128];
        int a3 = (lane < 8) ? act[lane + 192] : 0;
        int r0 = sb * 16 + wave * 4;
        float c0 = 0.f, c1 = 0.f, c2 = 0.f, c3 = 0.f;
        for (int i = 0; i < 4; i++) {
            const float* lr = logits + (size_t)(r0 + i) * NCLS;
            float x0 = lr[a0], x1 = lr[a1], x2 = lr[a2];
            float x3 = (lane < 8) ? lr[a3] : -3.0e38f;
            float m = fmaxf(fmaxf(x0, x1), fmaxf(x2, x3));
            #pragma unroll
            for (int s = 32; s > 0; s >>= 1) m = fmaxf(m, __shfl_xor(m, s));
            float e0 = __expf(x0 - m), e1 = __expf(x1 - m), e2 = __expf(x2 - m);
            float e3 = (lane < 8) ? __expf(x3 - m) : 0.f;
            float sm = e0 + e1 + e2 + e3;
            #pragma unroll
            for (int s = 32; s > 0; s >>= 1) sm += __shfl_xor(sm, s);
            float inv = 1.0f / sm;
            c0 += e0 * inv; c1 += e1 * inv; c2 += e2 * inv; c3 += e3 * inv;
        }
        accs[wave * 256 + lane] = c0; accs[wave * 256 + lane + 64] = c1;
        accs[wave * 256 + lane + 128] = c2;
        if (lane < 8) accs[wave * 256 + lane + 192] = c3;
        __syncthreads();
        mpart[(size_t)tid * 256 + sb] =
            accs[tid] + accs[256 + tid] + accs[512 + tid] + accs[768 + tid];
        return;
    }
    // ---- fz GEMM: 512 blocks, 64x64 tiles, K=768 ----
    {
        unsigned short* Al = (unsigned short*)shmem;           // 64 x 72
        unsigned short* Bl = Al + 64 * 72;
        int f = blockIdx.x - (B_N + 256);
        int which = f >> 8;                  // 0: f1, 1: f2
        int t6 = f & 255;
        int mBase = (t6 >> 2) * 64;
        int nBase = (t6 & 3) * 64;
        const float* wsrc = which ? w2 : w1;
        const float* bias = which ? b2 : b1;
        unsigned char* outz = which ? f2z8 : f1z8;
        int lane = tid & 63, wave = tid >> 6, quad = lane >> 4, col = lane & 15;
        v4f acc[4];
        #pragma unroll
        for (int i = 0; i < 4; i++) acc[i] = (v4f){0.f, 0.f, 0.f, 0.f};
        for (int kc = 0; kc < D_N; kc += 64) {
            __syncthreads();
            #pragma unroll
            for (int s = 0; s < 4; s++) {
                int slot = s * 256 + tid;
                int row = slot >> 4, k4 = slot & 15;
                float4 va = *(const float4*)(z + (size_t)(mBase + row) * D_N + kc + k4 * 4);
                float4 vb = *(const float4*)(wsrc + (size_t)(nBase + row) * D_N + kc + k4 * 4);
                unsigned short* pa = Al + row * 72 + k4 * 4;
                unsigned short* pb = Bl + row * 72 + k4 * 4;
                pa[0] = f2bf(va.x); pa[1] = f2bf(va.y); pa[2] = f2bf(va.z); pa[3] = f2bf(va.w);
                pb[0] = f2bf(vb.x); pb[1] = f2bf(vb.y); pb[2] = f2bf(vb.z); pb[3] = f2bf(vb.w);
            }
            __syncthreads();
            #pragma unroll
            for (int kk = 0; kk < 2; kk++) {
                v8s af = *(const v8s*)(Al + (wave * 16 + col) * 72 + kk * 32 + quad * 8);
                #pragma unroll
                for (int tc = 0; tc < 4; tc++) {
                    v8s bf = *(const v8s*)(Bl + (tc * 16 + col) * 72 + kk * 32 + quad * 8);
                    acc[tc] = __builtin_amdgcn_mfma_f32_16x16x32_bf16(af, bf, acc[tc], 0, 0, 0);
                }
            }
        }
        #pragma unroll
        for (int tc = 0; tc < 4; tc++) {
            int gcol = nBase + tc * 16 + col;
            float bv = bias[gcol];
            #pragma unroll
            for (int reg = 0; reg < 4; reg++) {
                int grow = mBase + wave * 16 + quad * 4 + reg;
                int sw8 = ((grow >> 3) & 1) << 3;      // half-swap key
                outz[(size_t)grow * HID_N + (gcol ^ sw8)] =
                    f2fp8(4.0f * (acc[tc][reg] + bv));
            }
        }
    }
}

// ---------------------------------------------------------------------------
// Kernel 2: fused contrastive main, fp8 (R11, unchanged). grid (32, 32).
// ---------------------------------------------------------------------------
__global__ __launch_bounds__(256, 2) void main_fused(
    const unsigned char* __restrict__ zn8, const unsigned char* __restrict__ bn8,
    const unsigned char* __restrict__ f1z8, const unsigned char* __restrict__ f2z8,
    float* __restrict__ partials)
{
    __shared__ __align__(16) unsigned char S[4 * 128 * 128];   // 64 KB
    unsigned char* S0 = S;
    unsigned char* S1 = S + 1 * 128 * 128;
    unsigned char* S2 = S + 2 * 128 * 128;
    unsigned char* S3 = S + 3 * 128 * 128;
    int tid = threadIdx.x, lane = tid & 63, wave = tid >> 6, quad = lane >> 4, col = lane & 15;
    int wr = wave >> 1, wc = wave & 1;
    int ib = blockIdx.x, jc = blockIdx.y;
    int rBase = ib * 128 + wr * 64;
    int cBase = jc * 128 + wc * 64;
    const int r8 = lane >> 3;
    const int kbl8 = (lane & 7) ^ r8;    // MS staging granule (16B) swizzle
    const int sub8 = ((quad & 1) ^ (col >> 3)) << 3;   // conflict-free sub-slot

    // ===== MS: mask (bn8) + sim (zn8), K=768 in 6 chunks of 128 =====
    v4f accB[4][4], accS[4][4];
    ZERO_ACC(accB); ZERO_ACC(accS);
    for (int kc = 0; kc < D_N; kc += 128) {
        __syncthreads();
        #pragma unroll
        for (int s = 0; s < 4; s++) {
            int rowbase = s * 32 + wave * 8;
            size_t rOff = (size_t)(ib * 128 + rowbase + r8) * D_N + kc + kbl8 * 16;
            size_t cOff = (size_t)(jc * 128 + rowbase + r8) * D_N + kc + kbl8 * 16;
            gld16c(bn8 + rOff, S0 + rowbase * 128);
            gld16c(bn8 + cOff, S1 + rowbase * 128);
            gld16c(zn8 + rOff, S2 + rowbase * 128);
            gld16c(zn8 + cOff, S3 + rowbase * 128);
        }
        __syncthreads();
        #pragma unroll
        for (int kk = 0; kk < 4; kk++) {
            int gbase = kk * 2 + (quad >> 1);
            int off = ((gbase ^ (col & 7)) << 4) + sub8;
            long a1[4], b1[4], a2[4], b2[4];
            #pragma unroll
            for (int t = 0; t < 4; t++) {
                int rA = (wr * 64 + t * 16 + col) * 128;
                int rB = (wc * 64 + t * 16 + col) * 128;
                a1[t] = *(const long*)(S0 + rA + off);
                b1[t] = *(const long*)(S1 + rB + off);
                a2[t] = *(const long*)(S2 + rA + off);
                b2[t] = *(const long*)(S3 + rB + off);
            }
            #pragma unroll
            for (int tr = 0; tr < 4; tr++)
                #pragma unroll
                for (int tc = 0; tc < 4; tc++) {
                    accB[tr][tc] = __builtin_amdgcn_mfma_f32_16x16x32_fp8_fp8(
                        a1[tr], b1[tc], accB[tr][tc], 0, 0, 0);
                    accS[tr][tc] = __builtin_amdgcn_mfma_f32_16x16x32_fp8_fp8(
                        a2[tr], b2[tc], accS[tr][tc], 0, 0, 0);
                }
        }
    }

    // ===== issue attn staging DMAs; epilogue VALU overlaps the DMA =====
    unsigned char* F1 = S0;               // 128 rows x 256 B
    unsigned char* F2 = S0 + 32768;
    __syncthreads();                      // all MS LDS reads complete
    {
        int r4 = lane >> 4;
        #pragma unroll
        for (int s = 0; s < 8; s++) {
            int rowbase = s * 16 + wave * 4;
            int row = rowbase + r4;
            int kb = (lane & 15) ^ (row & 15);
            gld16c(f1z8 + (size_t)(ib * 128 + row) * HID_N + kb * 16, F1 + rowbase * 256);
            gld16c(f2z8 + (size_t)(jc * 128 + row) * HID_N + kb * 16, F2 + rowbase * 256);
        }
    }

    // mask bits from accB (scale 16x16=256: threshold 0.05*256 = 12.8)
    unsigned long long mb = 0ull;
    #pragma unroll
    for (int tr = 0; tr < 4; tr++)
        #pragma unroll
        for (int tc = 0; tc < 4; tc++)
            #pragma unroll
            for (int reg = 0; reg < 4; reg++) {
                int grow = rBase + tr * 16 + quad * 4 + reg;
                int gcol = cBase + tc * 16 + col;
                if (accB[tr][tc][reg] > 12.8f && grow != gcol)
                    mb |= 1ull << (tr * 16 + tc * 4 + reg);
            }

    // dsum + packed bf16 sim values from accS (descale 1/256)
    float dsum[16];
    #pragma unroll
    for (int i = 0; i < 16; i++) dsum[i] = 0.f;
    unsigned int svp[4][4][2];
    #pragma unroll
    for (int tr = 0; tr < 4; tr++)
        #pragma unroll
        for (int tc = 0; tc < 4; tc++) {
            float s0 = accS[tr][tc][0] * 0.00390625f;
            float s1 = accS[tr][tc][1] * 0.00390625f;
            float s2 = accS[tr][tc][2] * 0.00390625f;
            float s3 = accS[tr][tc][3] * 0.00390625f;
            float svv[4] = {s0, s1, s2, s3};
            #pragma unroll
            for (int reg = 0; reg < 4; reg++) {
                int grow = rBase + tr * 16 + quad * 4 + reg;
                int gcol = cBase + tc * 16 + col;
                if (grow != gcol) dsum[tr * 4 + reg] += __expf(svv[reg] * 10.0f);
            }
            svp[tr][tc][0] = ((unsigned int)f2bf(s1) << 16) | f2bf(s0);
            svp[tr][tc][1] = ((unsigned int)f2bf(s3) << 16) | f2bf(s2);
        }

    // ===== attn: f1z8[ib] . f2z8[jc]^T, K=256 fully staged =====
    v4f accA[4][4]; ZERO_ACC(accA);
    __syncthreads();                      // DMA drained
    #pragma unroll
    for (int kk = 0; kk < 8; kk++) {
        int gbase = kk * 2 + (quad >> 1);
        int off = ((gbase ^ col) << 4) + sub8;
        long af[4], bf[4];
        #pragma unroll
        for (int t = 0; t < 4; t++) {
            af[t] = *(const long*)(F1 + (wr * 64 + t * 16 + col) * 256 + off);
            bf[t] = *(const long*)(F2 + (wc * 64 + t * 16 + col) * 256 + off);
        }
        #pragma unroll
        for (int tr = 0; tr < 4; tr++)
            #pragma unroll
            for (int tc = 0; tc < 4; tc++)
                accA[tr][tc] = __builtin_amdgcn_mfma_f32_16x16x32_fp8_fp8(
                    af[tr], bf[tc], accA[tr][tc], 0, 0, 0);
    }

    // ===== combine (attn scale 4x4=16: exp(acc/16)) =====
    float lsum[16], asum[16], nnf[16];
    #pragma unroll
    for (int i = 0; i < 16; i++) { lsum[i] = 0.f; asum[i] = 0.f; nnf[i] = 0.f; }
    #pragma unroll
    for (int tr = 0; tr < 4; tr++)
        #pragma unroll
        for (int tc = 0; tc < 4; tc++)
            #pragma unroll
            for (int reg = 0; reg < 4; reg++) {
                if ((mb >> (tr * 16 + tc * 4 + reg)) & 1ull) {
                    int slot = tr * 4 + reg;
                    float e = __expf(accA[tr][tc][reg] * 0.0625f);
                    unsigned int pk = svp[tr][tc][reg >> 1];
                    float sv = bf2f((unsigned short)((reg & 1) ? (pk >> 16) : (pk & 0xFFFF)));
                    lsum[slot] += e;
                    asum[slot] += e * sv;
                    nnf[slot] += 1.f;
                }
            }

    #pragma unroll
    for (int i = 0; i < 16; i++) {
        #pragma unroll
        for (int m = 1; m < 16; m <<= 1) {
            lsum[i] += __shfl_xor(lsum[i], m);
            asum[i] += __shfl_xor(asum[i], m);
            dsum[i] += __shfl_xor(dsum[i], m);
            nnf[i]  += __shfl_xor(nnf[i], m);
        }
        if (col == 0) {
            int row = rBase + (i >> 2) * 16 + quad * 4 + (i & 3);
            float4 v; v.x = lsum[i]; v.y = asum[i]; v.z = dsum[i]; v.w = nnf[i];
            *(float4*)(partials + ((size_t)row * 64 + jc * 2 + wc) * 4) = v;
        }
    }
}

// ---------------------------------------------------------------------------
// Kernel 3: reduce per-row partials; last block does entropy + combine.
// ---------------------------------------------------------------------------
__global__ __launch_bounds__(256) void row_reduce_fin(
    const float* __restrict__ partials, const float* __restrict__ mpart,
    float* __restrict__ acc, float* __restrict__ out)
{
    int tid = threadIdx.x;
    int row = blockIdx.x * 64 + (tid >> 2);
    int sub = tid & 3;
    const float4* p = (const float4*)partials + (size_t)row * 64 + sub * 16;
    float L = 0.f, A = 0.f, Dn = 0.f, NN = 0.f;
    #pragma unroll
    for (int c = 0; c < 16; c++) { float4 v = p[c]; L += v.x; A += v.y; Dn += v.z; NN += v.w; }
    #pragma unroll
    for (int m = 1; m < 4; m <<= 1) {
        L += __shfl_xor(L, m); A += __shfl_xor(A, m);
        Dn += __shfl_xor(Dn, m); NN += __shfl_xor(NN, m);
    }
    float per = 0.f, val = 0.f;
    if (sub == 0 && NN > 0.5f) {
        per = (logf(Dn + 1e-8f) - 10.0f * (A / L)) / NN;
        val = 1.0f;
    }
    __shared__ float red[256];
    __shared__ float r2s[256];
    __shared__ int amLast;
    red[tid] = per; r2s[tid] = val; __syncthreads();
    for (int s = 128; s > 0; s >>= 1) {
        if (tid < s) { red[tid] += red[tid + s]; r2s[tid] += r2s[tid + s]; }
        __syncthreads();
    }
    if (tid == 0) {
        atomicAdd(&acc[0], red[0]);
        atomicAdd(&acc[1], r2s[0]);
        __threadfence();
        int old = atomicAdd((int*)&acc[2], 1);
        amLast = (old == (int)gridDim.x - 1);
    }
    __syncthreads();
    if (!amLast) return;

    __shared__ float bcast[2];
    float pcl = 0.0f;
    if (tid < NCLS) {
        const float4* mp = (const float4*)(mpart + (size_t)tid * 256);
        float s = 0.f;
        #pragma unroll
        for (int c = 0; c < 64; c++) { float4 v = mp[c]; s += v.x + v.y + v.z + v.w; }
        pcl = s * (1.0f / 4096.0f);
    }
    red[tid] = (tid < 100) ? pcl : 0.0f; __syncthreads();
    for (int s = 128; s > 0; s >>= 1) { if (tid < s) red[tid] += red[tid + s]; __syncthreads(); }
    if (tid == 0) bcast[0] = red[0];
    __syncthreads();
    red[tid] = (tid >= 100 && tid < NCLS) ? pcl : 0.0f; __syncthreads();
    for (int s = 128; s > 0; s >>= 1) { if (tid < s) red[tid] += red[tid + s]; __syncthreads(); }
    if (tid == 0) bcast[1] = red[0];
    __syncthreads();
    float p_old = bcast[0], p_new = bcast[1];

    float t = 0.0f;
    if (tid < 100)       { float q = pcl / (p_old + 1e-8f); t = q * logf(q + 1e-8f); }
    else if (tid < NCLS) { float q = pcl / (p_new + 1e-8f); t = q * logf(q + 1e-8f); }
    red[tid] = t; __syncthreads();
    for (int s = 128; s > 0; s >>= 1) { if (tid < s) red[tid] += red[tid + s]; __syncthreads(); }

    if (tid == 0) {
        float s0 = __hip_atomic_load(&acc[0], __ATOMIC_RELAXED, __HIP_MEMORY_SCOPE_AGENT);
        float s1 = __hip_atomic_load(&acc[1], __ATOMIC_RELAXED, __HIP_MEMORY_SCOPE_AGENT);
        float loss_inter = p_old * logf(p_old + 1e-8f) + p_new * logf(p_new + 1e-8f)
                           + 0.69314718056f;
        float loss_entropy = loss_inter + red[0] + 2.0f * 4.60517018599f;
        float lc = (s1 > 0.5f) ? s0 / s1 : 0.0f;
        out[0] = loss_entropy + lc;
    }
}

// ---------------------------------------------------------------------------
extern "C" void kernel_launch(void* const* d_in, const int* in_sizes, int n_in,
                              void* d_out, int out_size, void* d_ws, size_t ws_size,
                              hipStream_t stream)
{
    const float* z_u    = (const float*)d_in[0];
    const float* logits = (const float*)d_in[1];
    const int*   oldi   = (const int*)d_in[2];
    const int*   newi   = (const int*)d_in[3];
    const float* basef  = (const float*)d_in[4];
    const float* f1w    = (const float*)d_in[5];
    const float* f1b    = (const float*)d_in[6];
    const float* f2w    = (const float*)d_in[7];
    const float* f2b    = (const float*)d_in[8];
    float* out = (float*)d_out;

    unsigned char* zn8   = (unsigned char*)d_ws;           // [B][D] fp8
    unsigned char* bn8   = zn8 + (size_t)B_N * D_N;
    unsigned char* f1z8  = bn8 + (size_t)B_N * D_N;        // [B][HID] fp8
    unsigned char* f2z8  = f1z8 + (size_t)B_N * HID_N;
    float* partials = (float*)(f2z8 + (size_t)B_N * HID_N); // [B][64][4]
    float* mpart    = partials + (size_t)B_N * 64 * 4;      // [256 class][256 blk]
    float* accums   = mpart + 256 * 256;                    // [2] + counter

    pre_all<<<B_N + 256 + 512, 256, 0, stream>>>(
        z_u, basef, f1w, f2w, f1b, f2b, logits, oldi, newi,
        zn8, bn8, f1z8, f2z8, mpart, accums);
    main_fused<<<dim3(32, 32), 256, 0, stream>>>(zn8, bn8, f1z8, f2z8, partials);
    row_reduce_fin<<<64, 256, 0, stream>>>(partials, mpart, accums, out);
}